// Round 7
// baseline (202.425 us; speedup 1.0000x reference)
//
#include <hip/hip_runtime.h>
#include <hip/hip_bf16.h>

#define BATCHN 512
#define NV 50
#define NE 2450
#define INSZ 16
#define MH 32
#define NH 256

typedef short s16x8 __attribute__((ext_vector_type(8)));
typedef float f32x4 __attribute__((ext_vector_type(4)));

#define PRED_OFF (BATCHN * NV * INSZ)   // 409600

// ---- ws layout (bytes) ----
// agg    f32 [B][V][32]      : 0        .. 3276800
// W2t    bf16 [3][32][32]    : 3276800  .. 3282944
// W1t    bf16 [2][3][32][32] : 3282944  .. 3295232
// Wt1sw  bf16 16384          : 3295232  .. 3328000   (swizzled LDS image, fc1)
// Wt2sw  bf16 65536          : 3328000  .. 3459072   (4 chunks of 16384)
// Wtmusw bf16 4096           : 3459072  .. 3467264

__device__ __forceinline__ unsigned short f2bf(float x) {
  unsigned int u = __float_as_uint(x);
  unsigned int r = (u + 0x7fffu + ((u >> 16) & 1u)) >> 16;  // RTNE
  return (unsigned short)r;
}
__device__ __forceinline__ unsigned int pk2(float a, float b) {
  return (unsigned int)f2bf(a) | ((unsigned int)f2bf(b) << 16);
}
__device__ __forceinline__ unsigned int cvtpk(float lo, float hi) {
  unsigned int r;
  asm("v_cvt_pk_bf16_f32 %0, %1, %2" : "=v"(r) : "v"(lo), "v"(hi));
  return r;
}
__device__ __forceinline__ unsigned int pkmax0(unsigned int x, unsigned int z) {
  unsigned int r;
  asm("v_pk_max_i16 %0, %1, %2" : "=v"(r) : "v"(x), "v"(z));
  return r;
}

// ---------------- Kernel 1: weight transforms -------------------
__global__ void k_tr(const float* __restrict__ w1, const float* __restrict__ w2,
                     const float* __restrict__ wo1, const float* __restrict__ wo2,
                     const float* __restrict__ wmu,
                     unsigned short* __restrict__ W2t, unsigned short* __restrict__ W1t,
                     unsigned short* __restrict__ Wt1sw, unsigned short* __restrict__ Wt2sw,
                     unsigned short* __restrict__ Wtmusw) {
  int idx = blockIdx.x * 256 + threadIdx.x;
  if (idx < 3072) {                      // W2t[kk][h][c] = w2[(kk+1)*32 + c][h]
    int c = idx & 31, h = (idx >> 5) & 31, kk = idx >> 10;
    W2t[idx] = f2bf(w2[((kk + 1) * 32 + c) * 32 + h]);
  } else if (idx < 9216) {               // W1t[half][kk][n][k]
    int j = idx - 3072;
    int k = j & 31, n = (j >> 5) & 31, kk = (j >> 10) % 3, half = j / 3072;
    W1t[j] = f2bf(k < 16 ? w1[((kk + 1) * 32 + half * 16 + k) * 32 + n] : 0.f);
  } else if (idx < 9216 + 16384) {       // Wt1sw: n 0..255, kl 0..63 (48.. zero), swizzled
    int j = idx - 9216; int n = j & 255, kl = j >> 8;
    float v = kl < 48 ? wo1[kl * 256 + n] : 0.f;
    Wt1sw[n * 64 + (kl ^ ((n & 7) << 3))] = f2bf(v);
  } else if (idx < 9216 + 16384 + 65536) { // Wt2sw: 4 chunks x (n 0..255, kl 0..63)
    int j = idx - (9216 + 16384);
    int c = j >> 14, r = j & 16383;
    int n = r & 255, kl = r >> 8;
    float v = wo2[(c * 64 + kl) * 256 + n];
    Wt2sw[(c * 256 + n) * 64 + (kl ^ ((n & 7) << 3))] = f2bf(v);
  } else if (idx < 9216 + 16384 + 65536 + 4096) { // Wtmusw: n 0..15, kl 0..255
    int j = idx - (9216 + 16384 + 65536);
    int n = j & 15, kl = j >> 4;
    Wtmusw[n * 256 + (kl ^ ((n & 7) << 3))] = f2bf(wmu[kl * 16 + n]);
  }
}

// ---------------- Kernel 2: fused fc1 + messages + scatter -------------------
// grid 512 (one block per batch), 1024 threads (16 waves) -> 2 blocks/CU =
// 32 waves/CU = 8 waves/SIMD (full occupancy). Wave w owns receivers
// j = w, w+16, ... with the full S table in registers. Slot == sender index;
// diagonal and slots >= 50 carry E = 0. No atomics; direct global stores.
__global__ void __launch_bounds__(1024, 8)
k_msg(const float* __restrict__ inputs, const float* __restrict__ edges,
      const float* __restrict__ b1, const float* __restrict__ b2,
      const unsigned short* __restrict__ W1t, const unsigned short* __restrict__ W2t,
      float* __restrict__ agg) {
  __shared__ __align__(16) float R_lds[NV * 100];   // f32, stride 100
  __shared__ __align__(16) float S_lds[NV * 100];   // f32, stride 100
  __shared__ __align__(16) float E_lds[NV * 156];   // [j][kk][52 slots]; slot==sender

  const int b   = blockIdx.x;
  const int tid = threadIdx.x;
  const int w   = tid >> 6;       // 0..15
  const int l   = tid & 63;
  const int grp = l >> 4;         // 0..3
  const int lm  = l & 15;

  // ---- stage edge coefficients; slot r IS the sender index (52 slots) ----
  for (int x = tid; x < NV * 52; x += 1024) {
    int r = x / 50;               // sender index 0..51
    int j = x - r * 50;           // receiver
    float4 ev = make_float4(0.f, 0.f, 0.f, 0.f);
    if (r < NV && r != j) {
      int e = r * 49 + j - (j > r ? 1 : 0);
      ev = reinterpret_cast<const float4*>(edges)[b * NE + e];
    }
    int base = j * 156 + r;
    E_lds[base]       = ev.y;     // edge types 1..3 only (SKIP_FIRST)
    E_lds[base + 52]  = ev.z;
    E_lds[base + 104] = ev.w;
  }

  // ---- in-block fc1 GEMM (waves 0..7): R/S = inputs @ W1 halves ----
  if (w < 8) {
    const int half = w >> 2;      // 0 = recv weights (R, +b1), 1 = send weights (S)
    const int mt4  = w & 3;       // node tile
    int node  = mt4 * 16 + lm;
    int nodec = node < NV ? node : NV - 1;
    s16x8 af = {0, 0, 0, 0, 0, 0, 0, 0};
    if (grp < 2) {
      const float4* ip = reinterpret_cast<const float4*>(inputs) + (b * NV + nodec) * 4 + grp * 2;
      float4 x0 = ip[0], x1 = ip[1];
      union { unsigned int u[4]; s16x8 v; } U;
      U.u[0] = cvtpk(x0.x, x0.y); U.u[1] = cvtpk(x0.z, x0.w);
      U.u[2] = cvtpk(x1.x, x1.y); U.u[3] = cvtpk(x1.z, x1.w);
      af = U.v;
    }
    float* dst = half ? S_lds : R_lds;
#pragma unroll
    for (int kk = 0; kk < 3; ++kk) {
#pragma unroll
      for (int nt = 0; nt < 2; ++nt) {
        int h = lm + 16 * nt;
        s16x8 bf = *reinterpret_cast<const s16x8*>(W1t + ((half * 3 + kk) * 32 + h) * 32 + grp * 8);
        f32x4 C;
        if (half == 0) { float bv = b1[(kk + 1) * 32 + h]; C = f32x4{bv, bv, bv, bv}; }
        else C = f32x4{0.f, 0.f, 0.f, 0.f};
        f32x4 o = __builtin_amdgcn_mfma_f32_16x16x32_bf16(af, bf, C, 0, 0, 0);
#pragma unroll
        for (int rr = 0; rr < 4; ++rr) {
          int n2 = mt4 * 16 + grp * 4 + rr;
          if (n2 < NV) dst[n2 * 100 + kk * 32 + h] = o[rr];
        }
      }
    }
  }

  // ---- per-wave persistent fragments (global reads, before barrier) ----
  s16x8 Bf[3][2];                 // W2 B-frags
  f32x4 Cb[3][2];                 // fc2 bias as MFMA C operand
#pragma unroll
  for (int kk = 0; kk < 3; ++kk)
#pragma unroll
    for (int nt = 0; nt < 2; ++nt) {
      int h = lm + 16 * nt;
      Bf[kk][nt] = *reinterpret_cast<const s16x8*>(W2t + (kk * 32 + h) * 32 + grp * 8);
      float bv = b2[(kk + 1) * 32 + h];
      Cb[kk][nt] = f32x4{bv, bv, bv, bv};
    }
  const unsigned int zero = 0;
  __syncthreads();

  // ---- load full S table into registers (row == sender index) ----
  float Sreg[4][3][8];
#pragma unroll
  for (int mt = 0; mt < 4; ++mt) {
    int srow = mt * 16 + lm;
    int src  = srow < NV ? srow : NV - 1;   // rows >=50 clamped; killed by E=0
#pragma unroll
    for (int kk = 0; kk < 3; ++kk) {
      const float* Sp = &S_lds[src * 100 + kk * 32 + grp * 8];
      f32x4 sA = *reinterpret_cast<const f32x4*>(Sp);
      f32x4 sB = *reinterpret_cast<const f32x4*>(Sp + 4);
#pragma unroll
      for (int p = 0; p < 4; ++p) { Sreg[mt][kk][p] = sA[p]; Sreg[mt][kk][4 + p] = sB[p]; }
    }
  }

  // ---- main loop: wave owns receivers j = w, w+16, ... (all senders) ----
  for (int j = w; j < NV; j += 16) {
    float s0a = 0.f, s0b = 0.f, s1a = 0.f, s1b = 0.f;
#pragma unroll
    for (int kk = 0; kk < 3; ++kk) {
      const float* Rp = &R_lds[j * 100 + kk * 32 + grp * 8];
      f32x4 rA = *reinterpret_cast<const f32x4*>(Rp);
      f32x4 rB = *reinterpret_cast<const f32x4*>(Rp + 4);
#pragma unroll
      for (int mt = 0; mt < 4; ++mt) {
        union { unsigned int u[4]; s16x8 v; } U;
        U.u[0] = pkmax0(cvtpk(Sreg[mt][kk][0] + rA[0], Sreg[mt][kk][1] + rA[1]), zero);
        U.u[1] = pkmax0(cvtpk(Sreg[mt][kk][2] + rA[2], Sreg[mt][kk][3] + rA[3]), zero);
        U.u[2] = pkmax0(cvtpk(Sreg[mt][kk][4] + rB[0], Sreg[mt][kk][5] + rB[1]), zero);
        U.u[3] = pkmax0(cvtpk(Sreg[mt][kk][6] + rB[2], Sreg[mt][kk][7] + rB[3]), zero);
        f32x4 a0 = __builtin_amdgcn_mfma_f32_16x16x32_bf16(U.v, Bf[kk][0], Cb[kk][0], 0, 0, 0);
        f32x4 a1 = __builtin_amdgcn_mfma_f32_16x16x32_bf16(U.v, Bf[kk][1], Cb[kk][1], 0, 0, 0);
        int sb = mt * 16 + grp * 4;             // slot base; mt==3,grp>0 dead
        f32x4 ev;
        if (mt < 3) {
          ev = *reinterpret_cast<const f32x4*>(&E_lds[j * 156 + kk * 52 + sb]);
        } else {
          ev = *reinterpret_cast<const f32x4*>(&E_lds[j * 156 + kk * 52 + 48]);
          if (grp) ev = f32x4{0.f, 0.f, 0.f, 0.f};
        }
        s0a = fmaf(fmaxf(a0[0], 0.f), ev[0], s0a);
        s0b = fmaf(fmaxf(a0[1], 0.f), ev[1], s0b);
        s0a = fmaf(fmaxf(a0[2], 0.f), ev[2], s0a);
        s0b = fmaf(fmaxf(a0[3], 0.f), ev[3], s0b);
        s1a = fmaf(fmaxf(a1[0], 0.f), ev[0], s1a);
        s1b = fmaf(fmaxf(a1[1], 0.f), ev[1], s1b);
        s1a = fmaf(fmaxf(a1[2], 0.f), ev[2], s1a);
        s1b = fmaf(fmaxf(a1[3], 0.f), ev[3], s1b);
      }
    }
    float s0 = s0a + s0b, s1 = s1a + s1b;
    s0 += __shfl_xor(s0, 16, 64); s0 += __shfl_xor(s0, 32, 64);
    s1 += __shfl_xor(s1, 16, 64); s1 += __shfl_xor(s1, 32, 64);
    if (l < 16)      agg[(b * NV + j) * MH + lm] = s0;
    else if (l < 32) agg[(b * NV + j) * MH + 16 + lm] = s1;
  }
}

// ---------------- Kernel 3: output MLP (fc1 -> fc2 -> mu), LDS-staged B ----------
// grid 400 blocks x 256 thr; block handles 64 rows of (b,v)
__global__ void __launch_bounds__(256, 3)
k_out(const float* __restrict__ inputs, const float* __restrict__ agg,
      const unsigned short* __restrict__ Wt1sw, const float* __restrict__ bo1,
      const unsigned short* __restrict__ Wt2sw, const float* __restrict__ bo2,
      const unsigned short* __restrict__ Wtmusw, const float* __restrict__ bmu,
      float* __restrict__ out) {
  __shared__ unsigned short aug[64 * 72];   // [row][c] 0..15 inputs, 16..47 agg, 48..63 zero
  __shared__ unsigned short P1[64 * 264];   // [row][n] padded 256->264
  __shared__ __align__(16) unsigned short WB[16384]; // 32KB swizzled B chunk

  const int tid = threadIdx.x;
  const int w   = tid >> 6;
  const int l   = tid & 63;
  const int grp = l >> 4;
  const int lm  = l & 15;
  const int gr0 = blockIdx.x * 64;
  const int xo  = (lm & 7) << 3;            // lane's swizzle term (n&7 == lm&7)

  // build aug tile (bf16) + stage Wt1sw chunk
  {
    int row = tid >> 2, q = tid & 3;
    int gr = gr0 + row;
    float4 iv = reinterpret_cast<const float4*>(inputs)[gr * 4 + q];
    uint2 u0; u0.x = pk2(iv.x, iv.y); u0.y = pk2(iv.z, iv.w);
    *reinterpret_cast<uint2*>(&aug[row * 72 + q * 4]) = u0;
    float4 a0 = reinterpret_cast<const float4*>(agg)[gr * 8 + q * 2];
    float4 a1 = reinterpret_cast<const float4*>(agg)[gr * 8 + q * 2 + 1];
    uint4 u1; u1.x = pk2(a0.x, a0.y); u1.y = pk2(a0.z, a0.w);
    u1.z = pk2(a1.x, a1.y); u1.w = pk2(a1.z, a1.w);
    *reinterpret_cast<uint4*>(&aug[row * 72 + 16 + q * 8]) = u1;
    uint2 uz; uz.x = 0u; uz.y = 0u;
    *reinterpret_cast<uint2*>(&aug[row * 72 + 48 + q * 4]) = uz;
  }
  {
    const uint4* src = reinterpret_cast<const uint4*>(Wt1sw);
    for (int i = tid; i < 2048; i += 256) reinterpret_cast<uint4*>(WB)[i] = src[i];
  }
  __syncthreads();

  const int rowA  = 16 * w + lm;    // A-fragment row
  const int kgrp  = grp * 8;        // A k-offset for this lane group
  const int rbase = 16 * w + grp * 4;

  // ---- fc1: aug[64x64] @ Wt1 -> P1 [64x256] ----
  f32x4 acc1[16];
#pragma unroll
  for (int nt = 0; nt < 16; ++nt) acc1[nt] = f32x4{0.f, 0.f, 0.f, 0.f};
#pragma unroll
  for (int kc = 0; kc < 2; ++kc) {
    s16x8 af = *reinterpret_cast<const s16x8*>(&aug[rowA * 72 + kc * 32 + kgrp]);
#pragma unroll
    for (int nt = 0; nt < 16; ++nt) {
      int n = lm + 16 * nt;
      s16x8 bf = *reinterpret_cast<const s16x8*>(&WB[n * 64 + ((kc * 32 + kgrp) ^ xo)]);
      acc1[nt] = __builtin_amdgcn_mfma_f32_16x16x32_bf16(af, bf, acc1[nt], 0, 0, 0);
    }
  }
#pragma unroll
  for (int nt = 0; nt < 16; ++nt) {
    int n = lm + 16 * nt;
    float bias = bo1[n];
#pragma unroll
    for (int rr = 0; rr < 4; ++rr) {
      float v = acc1[nt][rr] + bias; v = v > 0.f ? v : 0.f;
      P1[(rbase + rr) * 264 + n] = f2bf(v);
    }
  }
  __syncthreads();   // WB (Wt1) readers done before restage

  // ---- fc2: P1 @ Wt2 (4 staged chunks) ----
  f32x4 acc2[16];
#pragma unroll
  for (int nt = 0; nt < 16; ++nt) acc2[nt] = f32x4{0.f, 0.f, 0.f, 0.f};
  for (int c = 0; c < 4; ++c) {
    const uint4* src = reinterpret_cast<const uint4*>(Wt2sw + c * 16384);
    for (int i = tid; i < 2048; i += 256) reinterpret_cast<uint4*>(WB)[i] = src[i];
    __syncthreads();
#pragma unroll
    for (int kcl = 0; kcl < 2; ++kcl) {
      int kc = c * 2 + kcl;
      s16x8 af = *reinterpret_cast<const s16x8*>(&P1[rowA * 264 + kc * 32 + kgrp]);
#pragma unroll
      for (int nt = 0; nt < 16; ++nt) {
        int n = lm + 16 * nt;
        s16x8 bf = *reinterpret_cast<const s16x8*>(&WB[n * 64 + ((kcl * 32 + kgrp) ^ xo)]);
        acc2[nt] = __builtin_amdgcn_mfma_f32_16x16x32_bf16(af, bf, acc2[nt], 0, 0, 0);
      }
    }
    __syncthreads();
  }
#pragma unroll
  for (int nt = 0; nt < 16; ++nt) {
    int n = lm + 16 * nt;
    float bias = bo2[n];
#pragma unroll
    for (int rr = 0; rr < 4; ++rr) {
      float v = acc2[nt][rr] + bias; v = v > 0.f ? v : 0.f;
      out[PRED_OFF + (gr0 + rbase + rr) * 256 + n] = v;
      P1[(rbase + rr) * 264 + n] = f2bf(v);
    }
  }

  // ---- mu: pred @ Wtmu -> [64x16] ----
  {
    const uint4* src = reinterpret_cast<const uint4*>(Wtmusw);
    for (int i = tid; i < 512; i += 256) reinterpret_cast<uint4*>(WB)[i] = src[i];
  }
  __syncthreads();
  f32x4 accm = {0.f, 0.f, 0.f, 0.f};
#pragma unroll
  for (int kc = 0; kc < 8; ++kc) {
    s16x8 af = *reinterpret_cast<const s16x8*>(&P1[rowA * 264 + kc * 32 + kgrp]);
    s16x8 bf = *reinterpret_cast<const s16x8*>(&WB[lm * 256 + ((kc * 32 + kgrp) ^ xo)]);
    accm = __builtin_amdgcn_mfma_f32_16x16x32_bf16(af, bf, accm, 0, 0, 0);
  }
  {
    float bias = bmu[lm];
#pragma unroll
    for (int rr = 0; rr < 4; ++rr) {
      out[(gr0 + rbase + rr) * 16 + lm] = accm[rr] + bias;
    }
  }
}

extern "C" void kernel_launch(void* const* d_in, const int* in_sizes, int n_in,
                              void* d_out, int out_size, void* d_ws, size_t ws_size,
                              hipStream_t stream) {
  const float* inputs = (const float*)d_in[0];
  const float* edges  = (const float*)d_in[1];
  const float* w1     = (const float*)d_in[2];
  const float* b1     = (const float*)d_in[3];
  const float* w2     = (const float*)d_in[4];
  const float* b2     = (const float*)d_in[5];
  const float* wo1    = (const float*)d_in[6];
  const float* bo1    = (const float*)d_in[7];
  const float* wo2    = (const float*)d_in[8];
  const float* bo2    = (const float*)d_in[9];
  const float* wmu    = (const float*)d_in[10];
  const float* bmu    = (const float*)d_in[11];
  float* out = (float*)d_out;

  char* ws = (char*)d_ws;
  float*          agg    = (float*)(ws + 0);
  unsigned short* W2t    = (unsigned short*)(ws + 3276800);
  unsigned short* W1t    = (unsigned short*)(ws + 3282944);
  unsigned short* Wt1sw  = (unsigned short*)(ws + 3295232);
  unsigned short* Wt2sw  = (unsigned short*)(ws + 3328000);
  unsigned short* Wtmusw = (unsigned short*)(ws + 3459072);

  k_tr<<<372, 256, 0, stream>>>(w1, w2, wo1, wo2, wmu, W2t, W1t, Wt1sw, Wt2sw, Wtmusw);
  k_msg<<<512, 1024, 0, stream>>>(inputs, edges, b1, b2, W1t, W2t, agg);
  k_out<<<400, 256, 0, stream>>>(inputs, agg, Wt1sw, bo1, Wt2sw, bo2, Wtmusw, bmu, out);
}

// Round 8
// 71.957 us; speedup vs baseline: 2.8132x; 2.8132x over previous
//
#include <hip/hip_runtime.h>
#include <hip/hip_bf16.h>

#define BATCHN 512
#define NV 50
#define NE 2450
#define INSZ 16
#define MH 32
#define NH 256

typedef short s16x8 __attribute__((ext_vector_type(8)));
typedef float f32x4 __attribute__((ext_vector_type(4)));

#define PRED_OFF (BATCHN * NV * INSZ)   // 409600

// ---- ws layout (bytes) ----
// agg    f32 [B][V][32]      : 0        .. 3276800
// W2t    bf16 [3][32][32]    : 3276800  .. 3282944
// W1t    bf16 [2][3][32][32] : 3282944  .. 3295232
// Wt1sw  bf16 16384          : 3295232  .. 3328000   (swizzled LDS image, fc1)
// Wt2sw  bf16 65536          : 3328000  .. 3459072   (4 chunks of 16384)
// Wtmusw bf16 4096           : 3459072  .. 3467264

__device__ __forceinline__ unsigned short f2bf(float x) {
  unsigned int u = __float_as_uint(x);
  unsigned int r = (u + 0x7fffu + ((u >> 16) & 1u)) >> 16;  // RTNE
  return (unsigned short)r;
}
__device__ __forceinline__ unsigned int pk2(float a, float b) {
  return (unsigned int)f2bf(a) | ((unsigned int)f2bf(b) << 16);
}
__device__ __forceinline__ unsigned int cvtpk(float lo, float hi) {
  unsigned int r;
  asm("v_cvt_pk_bf16_f32 %0, %1, %2" : "=v"(r) : "v"(lo), "v"(hi));
  return r;
}
__device__ __forceinline__ unsigned int pkmax0(unsigned int x, unsigned int z) {
  unsigned int r;
  asm("v_pk_max_i16 %0, %1, %2" : "=v"(r) : "v"(x), "v"(z));
  return r;
}

// ---------------- Kernel 1: weight transforms -------------------
__global__ void k_tr(const float* __restrict__ w1, const float* __restrict__ w2,
                     const float* __restrict__ wo1, const float* __restrict__ wo2,
                     const float* __restrict__ wmu,
                     unsigned short* __restrict__ W2t, unsigned short* __restrict__ W1t,
                     unsigned short* __restrict__ Wt1sw, unsigned short* __restrict__ Wt2sw,
                     unsigned short* __restrict__ Wtmusw) {
  int idx = blockIdx.x * 256 + threadIdx.x;
  if (idx < 3072) {                      // W2t[kk][h][c] = w2[(kk+1)*32 + c][h]
    int c = idx & 31, h = (idx >> 5) & 31, kk = idx >> 10;
    W2t[idx] = f2bf(w2[((kk + 1) * 32 + c) * 32 + h]);
  } else if (idx < 9216) {               // W1t[half][kk][n][k]
    int j = idx - 3072;
    int k = j & 31, n = (j >> 5) & 31, kk = (j >> 10) % 3, half = j / 3072;
    W1t[j] = f2bf(k < 16 ? w1[((kk + 1) * 32 + half * 16 + k) * 32 + n] : 0.f);
  } else if (idx < 9216 + 16384) {       // Wt1sw: n 0..255, kl 0..63 (48.. zero), swizzled
    int j = idx - 9216; int n = j & 255, kl = j >> 8;
    float v = kl < 48 ? wo1[kl * 256 + n] : 0.f;
    Wt1sw[n * 64 + (kl ^ ((n & 7) << 3))] = f2bf(v);
  } else if (idx < 9216 + 16384 + 65536) { // Wt2sw: 4 chunks x (n 0..255, kl 0..63)
    int j = idx - (9216 + 16384);
    int c = j >> 14, r = j & 16383;
    int n = r & 255, kl = r >> 8;
    float v = wo2[(c * 64 + kl) * 256 + n];
    Wt2sw[(c * 256 + n) * 64 + (kl ^ ((n & 7) << 3))] = f2bf(v);
  } else if (idx < 9216 + 16384 + 65536 + 4096) { // Wtmusw: n 0..15, kl 0..255
    int j = idx - (9216 + 16384 + 65536);
    int n = j & 15, kl = j >> 4;
    Wtmusw[n * 256 + (kl ^ ((n & 7) << 3))] = f2bf(wmu[kl * 16 + n]);
  }
}

// ---------------- Kernel 2: fused fc1 + messages + scatter -------------------
// grid 512 (one block per batch), 1024 threads (16 waves) -> 2 blocks/CU =
// 32 waves/CU = 8 waves/SIMD (full occupancy). Per-wave state is R5-sized
// (ONE mt sender tile in registers, ~24 VGPR): wave = (mt = w&3, jq = w>>2);
// jq owns ~12-13 receivers; 4 mt-waves combine via LDS atomicAdd.
// Slot == sender index; diagonal and slots >= 50 carry E = 0.
__global__ void __launch_bounds__(1024, 4)
k_msg(const float* __restrict__ inputs, const float* __restrict__ edges,
      const float* __restrict__ b1, const float* __restrict__ b2,
      const unsigned short* __restrict__ W1t, const unsigned short* __restrict__ W2t,
      float* __restrict__ agg) {
  __shared__ __align__(16) float R_lds[NV * 100];   // f32, stride 100
  __shared__ __align__(16) float S_lds[NV * 100];   // f32, stride 100
  __shared__ __align__(16) float E_lds[NV * 156];   // [j][kk][52 slots]; slot==sender
  __shared__ float agg_l[NV * 32];

  const int b   = blockIdx.x;
  const int tid = threadIdx.x;
  const int w   = tid >> 6;       // 0..15
  const int l   = tid & 63;
  const int grp = l >> 4;         // 0..3
  const int lm  = l & 15;

  // ---- stage edge coefficients; slot r IS the sender index (52 slots) ----
  for (int x = tid; x < NV * 52; x += 1024) {
    int r = x / 50;               // sender index 0..51
    int j = x - r * 50;           // receiver
    float4 ev = make_float4(0.f, 0.f, 0.f, 0.f);
    if (r < NV && r != j) {
      int e = r * 49 + j - (j > r ? 1 : 0);
      ev = reinterpret_cast<const float4*>(edges)[b * NE + e];
    }
    int base = j * 156 + r;
    E_lds[base]       = ev.y;     // edge types 1..3 only (SKIP_FIRST)
    E_lds[base + 52]  = ev.z;
    E_lds[base + 104] = ev.w;
  }
  for (int x = tid; x < NV * 32; x += 1024) agg_l[x] = 0.f;

  // ---- in-block fc1 GEMM (waves 0..7): R/S = inputs @ W1 halves ----
  if (w < 8) {
    const int half = w >> 2;      // 0 = recv weights (R, +b1), 1 = send weights (S)
    const int mt4  = w & 3;       // node tile
    int node  = mt4 * 16 + lm;
    int nodec = node < NV ? node : NV - 1;
    s16x8 af = {0, 0, 0, 0, 0, 0, 0, 0};
    if (grp < 2) {
      const float4* ip = reinterpret_cast<const float4*>(inputs) + (b * NV + nodec) * 4 + grp * 2;
      float4 x0 = ip[0], x1 = ip[1];
      union { unsigned int u[4]; s16x8 v; } U;
      U.u[0] = cvtpk(x0.x, x0.y); U.u[1] = cvtpk(x0.z, x0.w);
      U.u[2] = cvtpk(x1.x, x1.y); U.u[3] = cvtpk(x1.z, x1.w);
      af = U.v;
    }
    float* dst = half ? S_lds : R_lds;
#pragma unroll
    for (int kk = 0; kk < 3; ++kk) {
#pragma unroll
      for (int nt = 0; nt < 2; ++nt) {
        int h = lm + 16 * nt;
        s16x8 bf = *reinterpret_cast<const s16x8*>(W1t + ((half * 3 + kk) * 32 + h) * 32 + grp * 8);
        f32x4 C;
        if (half == 0) { float bv = b1[(kk + 1) * 32 + h]; C = f32x4{bv, bv, bv, bv}; }
        else C = f32x4{0.f, 0.f, 0.f, 0.f};
        f32x4 o = __builtin_amdgcn_mfma_f32_16x16x32_bf16(af, bf, C, 0, 0, 0);
#pragma unroll
        for (int rr = 0; rr < 4; ++rr) {
          int n2 = mt4 * 16 + grp * 4 + rr;
          if (n2 < NV) dst[n2 * 100 + kk * 32 + h] = o[rr];
        }
      }
    }
  }

  // ---- per-wave persistent fragments (global reads, before barrier) ----
  s16x8 Bf[3][2];                 // W2 B-frags (24 VGPR)
  float cb[3][2];                 // fc2 bias scalars (6 VGPR; expand at MFMA)
#pragma unroll
  for (int kk = 0; kk < 3; ++kk)
#pragma unroll
    for (int nt = 0; nt < 2; ++nt) {
      int h = lm + 16 * nt;
      Bf[kk][nt] = *reinterpret_cast<const s16x8*>(W2t + (kk * 32 + h) * 32 + grp * 8);
      cb[kk][nt] = b2[(kk + 1) * 32 + h];
    }
  const unsigned int zero = 0;
  __syncthreads();

  // ---- load this wave's S-tile into registers (once, f32; row == sender) ----
  const int mt = w & 3;
  const int jq = w >> 2;          // 0..3
  int srow = mt * 16 + lm;
  int src  = srow < NV ? srow : NV - 1;   // rows >=50 clamped; killed by E=0
  float Sreg[3][8];
#pragma unroll
  for (int kk = 0; kk < 3; ++kk) {
    const float* Sp = &S_lds[src * 100 + kk * 32 + grp * 8];
    f32x4 sA = *reinterpret_cast<const f32x4*>(Sp);
    f32x4 sB = *reinterpret_cast<const f32x4*>(Sp + 4);
#pragma unroll
    for (int p = 0; p < 4; ++p) { Sreg[kk][p] = sA[p]; Sreg[kk][4 + p] = sB[p]; }
  }

  // E-slot base for this lane; mt==3, grp>0 lanes are entirely dead (>= 52)
  const int sbase = mt * 16 + grp * 4;
  const bool dead = sbase > 48;
  const int sb    = dead ? 48 : sbase;

  // receiver range for jq: 13,13,12,12
  const int j0   = jq < 2 ? jq * 13 : 26 + (jq - 2) * 12;
  const int jend = j0 + (jq < 2 ? 13 : 12);

  // ---- main loop: this wave's sender tile x its receiver range ----
  for (int j = j0; j < jend; ++j) {
    float s0 = 0.f, s1 = 0.f;
#pragma unroll
    for (int kk = 0; kk < 3; ++kk) {
      const float* Rp = &R_lds[j * 100 + kk * 32 + grp * 8];
      f32x4 rA = *reinterpret_cast<const f32x4*>(Rp);
      f32x4 rB = *reinterpret_cast<const f32x4*>(Rp + 4);
      union { unsigned int u[4]; s16x8 v; } U;
      U.u[0] = pkmax0(cvtpk(Sreg[kk][0] + rA[0], Sreg[kk][1] + rA[1]), zero);
      U.u[1] = pkmax0(cvtpk(Sreg[kk][2] + rA[2], Sreg[kk][3] + rA[3]), zero);
      U.u[2] = pkmax0(cvtpk(Sreg[kk][4] + rB[0], Sreg[kk][5] + rB[1]), zero);
      U.u[3] = pkmax0(cvtpk(Sreg[kk][6] + rB[2], Sreg[kk][7] + rB[3]), zero);
      f32x4 C0 = f32x4{cb[kk][0], cb[kk][0], cb[kk][0], cb[kk][0]};
      f32x4 C1 = f32x4{cb[kk][1], cb[kk][1], cb[kk][1], cb[kk][1]};
      f32x4 a0 = __builtin_amdgcn_mfma_f32_16x16x32_bf16(U.v, Bf[kk][0], C0, 0, 0, 0);
      f32x4 a1 = __builtin_amdgcn_mfma_f32_16x16x32_bf16(U.v, Bf[kk][1], C1, 0, 0, 0);
      f32x4 ev = *reinterpret_cast<const f32x4*>(&E_lds[j * 156 + kk * 52 + sb]);
      if (dead) ev = f32x4{0.f, 0.f, 0.f, 0.f};
#pragma unroll
      for (int rr = 0; rr < 4; ++rr) {
        s0 = fmaf(fmaxf(a0[rr], 0.f), ev[rr], s0);
        s1 = fmaf(fmaxf(a1[rr], 0.f), ev[rr], s1);
      }
    }
    s0 += __shfl_xor(s0, 16, 64); s0 += __shfl_xor(s0, 32, 64);
    s1 += __shfl_xor(s1, 16, 64); s1 += __shfl_xor(s1, 32, 64);
    if (l < 16)      atomicAdd(&agg_l[j * 32 + lm], s0);
    else if (l < 32) atomicAdd(&agg_l[j * 32 + 16 + lm], s1);
  }
  __syncthreads();
  for (int x = tid; x < NV * 32; x += 1024) agg[b * (NV * 32) + x] = agg_l[x];
}

// ---------------- Kernel 3: output MLP (fc1 -> fc2 -> mu), LDS-staged B ----------
// grid 400 blocks x 256 thr; block handles 64 rows of (b,v)
__global__ void __launch_bounds__(256, 3)
k_out(const float* __restrict__ inputs, const float* __restrict__ agg,
      const unsigned short* __restrict__ Wt1sw, const float* __restrict__ bo1,
      const unsigned short* __restrict__ Wt2sw, const float* __restrict__ bo2,
      const unsigned short* __restrict__ Wtmusw, const float* __restrict__ bmu,
      float* __restrict__ out) {
  __shared__ unsigned short aug[64 * 72];   // [row][c] 0..15 inputs, 16..47 agg, 48..63 zero
  __shared__ unsigned short P1[64 * 264];   // [row][n] padded 256->264
  __shared__ __align__(16) unsigned short WB[16384]; // 32KB swizzled B chunk

  const int tid = threadIdx.x;
  const int w   = tid >> 6;
  const int l   = tid & 63;
  const int grp = l >> 4;
  const int lm  = l & 15;
  const int gr0 = blockIdx.x * 64;
  const int xo  = (lm & 7) << 3;            // lane's swizzle term (n&7 == lm&7)

  // build aug tile (bf16) + stage Wt1sw chunk
  {
    int row = tid >> 2, q = tid & 3;
    int gr = gr0 + row;
    float4 iv = reinterpret_cast<const float4*>(inputs)[gr * 4 + q];
    uint2 u0; u0.x = pk2(iv.x, iv.y); u0.y = pk2(iv.z, iv.w);
    *reinterpret_cast<uint2*>(&aug[row * 72 + q * 4]) = u0;
    float4 a0 = reinterpret_cast<const float4*>(agg)[gr * 8 + q * 2];
    float4 a1 = reinterpret_cast<const float4*>(agg)[gr * 8 + q * 2 + 1];
    uint4 u1; u1.x = pk2(a0.x, a0.y); u1.y = pk2(a0.z, a0.w);
    u1.z = pk2(a1.x, a1.y); u1.w = pk2(a1.z, a1.w);
    *reinterpret_cast<uint4*>(&aug[row * 72 + 16 + q * 8]) = u1;
    uint2 uz; uz.x = 0u; uz.y = 0u;
    *reinterpret_cast<uint2*>(&aug[row * 72 + 48 + q * 4]) = uz;
  }
  {
    const uint4* src = reinterpret_cast<const uint4*>(Wt1sw);
    for (int i = tid; i < 2048; i += 256) reinterpret_cast<uint4*>(WB)[i] = src[i];
  }
  __syncthreads();

  const int rowA  = 16 * w + lm;    // A-fragment row
  const int kgrp  = grp * 8;        // A k-offset for this lane group
  const int rbase = 16 * w + grp * 4;

  // ---- fc1: aug[64x64] @ Wt1 -> P1 [64x256] ----
  f32x4 acc1[16];
#pragma unroll
  for (int nt = 0; nt < 16; ++nt) acc1[nt] = f32x4{0.f, 0.f, 0.f, 0.f};
#pragma unroll
  for (int kc = 0; kc < 2; ++kc) {
    s16x8 af = *reinterpret_cast<const s16x8*>(&aug[rowA * 72 + kc * 32 + kgrp]);
#pragma unroll
    for (int nt = 0; nt < 16; ++nt) {
      int n = lm + 16 * nt;
      s16x8 bf = *reinterpret_cast<const s16x8*>(&WB[n * 64 + ((kc * 32 + kgrp) ^ xo)]);
      acc1[nt] = __builtin_amdgcn_mfma_f32_16x16x32_bf16(af, bf, acc1[nt], 0, 0, 0);
    }
  }
#pragma unroll
  for (int nt = 0; nt < 16; ++nt) {
    int n = lm + 16 * nt;
    float bias = bo1[n];
#pragma unroll
    for (int rr = 0; rr < 4; ++rr) {
      float v = acc1[nt][rr] + bias; v = v > 0.f ? v : 0.f;
      P1[(rbase + rr) * 264 + n] = f2bf(v);
    }
  }
  __syncthreads();   // WB (Wt1) readers done before restage

  // ---- fc2: P1 @ Wt2 (4 staged chunks) ----
  f32x4 acc2[16];
#pragma unroll
  for (int nt = 0; nt < 16; ++nt) acc2[nt] = f32x4{0.f, 0.f, 0.f, 0.f};
  for (int c = 0; c < 4; ++c) {
    const uint4* src = reinterpret_cast<const uint4*>(Wt2sw + c * 16384);
    for (int i = tid; i < 2048; i += 256) reinterpret_cast<uint4*>(WB)[i] = src[i];
    __syncthreads();
#pragma unroll
    for (int kcl = 0; kcl < 2; ++kcl) {
      int kc = c * 2 + kcl;
      s16x8 af = *reinterpret_cast<const s16x8*>(&P1[rowA * 264 + kc * 32 + kgrp]);
#pragma unroll
      for (int nt = 0; nt < 16; ++nt) {
        int n = lm + 16 * nt;
        s16x8 bf = *reinterpret_cast<const s16x8*>(&WB[n * 64 + ((kcl * 32 + kgrp) ^ xo)]);
        acc2[nt] = __builtin_amdgcn_mfma_f32_16x16x32_bf16(af, bf, acc2[nt], 0, 0, 0);
      }
    }
    __syncthreads();
  }
#pragma unroll
  for (int nt = 0; nt < 16; ++nt) {
    int n = lm + 16 * nt;
    float bias = bo2[n];
#pragma unroll
    for (int rr = 0; rr < 4; ++rr) {
      float v = acc2[nt][rr] + bias; v = v > 0.f ? v : 0.f;
      out[PRED_OFF + (gr0 + rbase + rr) * 256 + n] = v;
      P1[(rbase + rr) * 264 + n] = f2bf(v);
    }
  }

  // ---- mu: pred @ Wtmu -> [64x16] ----
  {
    const uint4* src = reinterpret_cast<const uint4*>(Wtmusw);
    for (int i = tid; i < 512; i += 256) reinterpret_cast<uint4*>(WB)[i] = src[i];
  }
  __syncthreads();
  f32x4 accm = {0.f, 0.f, 0.f, 0.f};
#pragma unroll
  for (int kc = 0; kc < 8; ++kc) {
    s16x8 af = *reinterpret_cast<const s16x8*>(&P1[rowA * 264 + kc * 32 + kgrp]);
    s16x8 bf = *reinterpret_cast<const s16x8*>(&WB[lm * 256 + ((kc * 32 + kgrp) ^ xo)]);
    accm = __builtin_amdgcn_mfma_f32_16x16x32_bf16(af, bf, accm, 0, 0, 0);
  }
  {
    float bias = bmu[lm];
#pragma unroll
    for (int rr = 0; rr < 4; ++rr) {
      out[(gr0 + rbase + rr) * 16 + lm] = accm[rr] + bias;
    }
  }
}

extern "C" void kernel_launch(void* const* d_in, const int* in_sizes, int n_in,
                              void* d_out, int out_size, void* d_ws, size_t ws_size,
                              hipStream_t stream) {
  const float* inputs = (const float*)d_in[0];
  const float* edges  = (const float*)d_in[1];
  const float* w1     = (const float*)d_in[2];
  const float* b1     = (const float*)d_in[3];
  const float* w2     = (const float*)d_in[4];
  const float* b2     = (const float*)d_in[5];
  const float* wo1    = (const float*)d_in[6];
  const float* bo1    = (const float*)d_in[7];
  const float* wo2    = (const float*)d_in[8];
  const float* bo2    = (const float*)d_in[9];
  const float* wmu    = (const float*)d_in[10];
  const float* bmu    = (const float*)d_in[11];
  float* out = (float*)d_out;

  char* ws = (char*)d_ws;
  float*          agg    = (float*)(ws + 0);
  unsigned short* W2t    = (unsigned short*)(ws + 3276800);
  unsigned short* W1t    = (unsigned short*)(ws + 3282944);
  unsigned short* Wt1sw  = (unsigned short*)(ws + 3295232);
  unsigned short* Wt2sw  = (unsigned short*)(ws + 3328000);
  unsigned short* Wtmusw = (unsigned short*)(ws + 3459072);

  k_tr<<<372, 256, 0, stream>>>(w1, w2, wo1, wo2, wmu, W2t, W1t, Wt1sw, Wt2sw, Wtmusw);
  k_msg<<<512, 1024, 0, stream>>>(inputs, edges, b1, b2, W1t, W2t, agg);
  k_out<<<400, 256, 0, stream>>>(inputs, agg, Wt1sw, bo1, Wt2sw, bo2, Wtmusw, bmu, out);
}

// Round 9
// 70.894 us; speedup vs baseline: 2.8553x; 1.0150x over previous
//
#include <hip/hip_runtime.h>
#include <hip/hip_bf16.h>

#define BATCHN 512
#define NV 50
#define NE 2450
#define INSZ 16
#define MH 32
#define NH 256

typedef short s16x8 __attribute__((ext_vector_type(8)));
typedef float f32x4 __attribute__((ext_vector_type(4)));

#define PRED_OFF (BATCHN * NV * INSZ)   // 409600

// ---- ws layout (bytes) ----
// agg    f32 [B][V][32]      : 0        .. 3276800
// W2t    bf16 [3][32][32]    : 3276800  .. 3282944
// W1t    bf16 [2][3][32][32] : 3282944  .. 3295232
// Wt1sw  bf16 16384          : 3295232  .. 3328000
// Wt2sw  bf16 65536          : 3328000  .. 3459072
// Wtmusw bf16 4096           : 3459072  .. 3467264

__device__ __forceinline__ unsigned short f2bf(float x) {
  unsigned int u = __float_as_uint(x);
  unsigned int r = (u + 0x7fffu + ((u >> 16) & 1u)) >> 16;  // RTNE
  return (unsigned short)r;
}
__device__ __forceinline__ unsigned int pk2(float a, float b) {
  return (unsigned int)f2bf(a) | ((unsigned int)f2bf(b) << 16);
}
__device__ __forceinline__ unsigned int cvtpk(float lo, float hi) {
  unsigned int r;
  asm("v_cvt_pk_bf16_f32 %0, %1, %2" : "=v"(r) : "v"(lo), "v"(hi));
  return r;
}
__device__ __forceinline__ unsigned int pkmax0(unsigned int x, unsigned int z) {
  unsigned int r;
  asm("v_pk_max_i16 %0, %1, %2" : "=v"(r) : "v"(x), "v"(z));
  return r;
}

// ---------------- Kernel 1: weight transforms -------------------
__global__ void k_tr(const float* __restrict__ w1, const float* __restrict__ w2,
                     const float* __restrict__ wo1, const float* __restrict__ wo2,
                     const float* __restrict__ wmu,
                     unsigned short* __restrict__ W2t, unsigned short* __restrict__ W1t,
                     unsigned short* __restrict__ Wt1sw, unsigned short* __restrict__ Wt2sw,
                     unsigned short* __restrict__ Wtmusw) {
  int idx = blockIdx.x * 256 + threadIdx.x;
  if (idx < 3072) {                      // W2t[kk][h][c] = w2[(kk+1)*32 + c][h]
    int c = idx & 31, h = (idx >> 5) & 31, kk = idx >> 10;
    W2t[idx] = f2bf(w2[((kk + 1) * 32 + c) * 32 + h]);
  } else if (idx < 9216) {               // W1t[half][kk][n][k]
    int j = idx - 3072;
    int k = j & 31, n = (j >> 5) & 31, kk = (j >> 10) % 3, half = j / 3072;
    W1t[j] = f2bf(k < 16 ? w1[((kk + 1) * 32 + half * 16 + k) * 32 + n] : 0.f);
  } else if (idx < 9216 + 16384) {       // Wt1sw
    int j = idx - 9216; int n = j & 255, kl = j >> 8;
    float v = kl < 48 ? wo1[kl * 256 + n] : 0.f;
    Wt1sw[n * 64 + (kl ^ ((n & 7) << 3))] = f2bf(v);
  } else if (idx < 9216 + 16384 + 65536) { // Wt2sw
    int j = idx - (9216 + 16384);
    int c = j >> 14, r = j & 16383;
    int n = r & 255, kl = r >> 8;
    float v = wo2[(c * 64 + kl) * 256 + n];
    Wt2sw[(c * 256 + n) * 64 + (kl ^ ((n & 7) << 3))] = f2bf(v);
  } else if (idx < 9216 + 16384 + 65536 + 4096) { // Wtmusw
    int j = idx - (9216 + 16384 + 65536);
    int n = j & 15, kl = j >> 4;
    Wtmusw[n * 256 + (kl ^ ((n & 7) << 3))] = f2bf(wmu[kl * 16 + n]);
  }
}

// ---------------- Kernel 2: fused fc1 + messages + scatter (scheme-D) --------
// grid (512 batches, 5 j-groups), 256 threads (4 waves). Each block: 10
// receivers x all senders. Wave w = sender tile mt; S tile computed in-block
// into a per-wave-private f32 LDS region then held in registers; R computed
// in-block for the 16-row window [j0, j0+16). Per-wave j-rotation de-phases
// the 4 waves. Slot == sender index; diagonal/out-of-range slots carry E=0.
__global__ void __launch_bounds__(256, 4)
k_msg(const float* __restrict__ inputs, const float* __restrict__ edges,
      const float* __restrict__ b1, const float* __restrict__ b2,
      const unsigned short* __restrict__ W1t, const unsigned short* __restrict__ W2t,
      float* __restrict__ agg) {
  __shared__ __align__(16) float S_l[4 * 16 * 100];  // per-wave-private tiles
  __shared__ __align__(16) float R_lds[10 * 100];    // f32, stride 100
  __shared__ __align__(16) float E_lds[10 * 156];    // [jl][kk][52 slots]
  __shared__ float agg_l[10 * 32];

  const int b   = blockIdx.x;
  const int j0  = blockIdx.y * 10;
  const int tid = threadIdx.x;
  const int w   = tid >> 6;       // 0..3 == mt (sender tile)
  const int l   = tid & 63;
  const int grp = l >> 4;         // 0..3
  const int lm  = l & 15;

  // ---- stage edge coefficients for this block's 10 receivers ----
  for (int x = tid; x < 520; x += 256) {
    int r  = x / 10;              // sender index 0..51
    int jl = x - r * 10;
    int j  = j0 + jl;
    float4 ev = make_float4(0.f, 0.f, 0.f, 0.f);
    if (r < NV && r != j) {
      int e = r * 49 + j - (j > r ? 1 : 0);
      ev = reinterpret_cast<const float4*>(edges)[b * NE + e];
    }
    int base = jl * 156 + r;
    E_lds[base]       = ev.y;     // edge types 1..3 only (SKIP_FIRST)
    E_lds[base + 52]  = ev.z;
    E_lds[base + 104] = ev.w;
  }
  for (int x = tid; x < 320; x += 256) agg_l[x] = 0.f;

  // ---- in-block fc1: S for this wave's sender tile (half=1, no bias) ----
  {
    int node  = w * 16 + lm;
    int nodec = node < NV ? node : NV - 1;
    s16x8 af = {0, 0, 0, 0, 0, 0, 0, 0};
    if (grp < 2) {
      const float4* ip = reinterpret_cast<const float4*>(inputs) + (b * NV + nodec) * 4 + grp * 2;
      float4 x0 = ip[0], x1 = ip[1];
      union { unsigned int u[4]; s16x8 v; } U;
      U.u[0] = cvtpk(x0.x, x0.y); U.u[1] = cvtpk(x0.z, x0.w);
      U.u[2] = cvtpk(x1.x, x1.y); U.u[3] = cvtpk(x1.z, x1.w);
      af = U.v;
    }
    float* dst = &S_l[w * 1600];
#pragma unroll
    for (int kk = 0; kk < 3; ++kk) {
#pragma unroll
      for (int nt = 0; nt < 2; ++nt) {
        int h = lm + 16 * nt;
        s16x8 bf = *reinterpret_cast<const s16x8*>(W1t + ((3 + kk) * 32 + h) * 32 + grp * 8);
        f32x4 C = f32x4{0.f, 0.f, 0.f, 0.f};
        f32x4 o = __builtin_amdgcn_mfma_f32_16x16x32_bf16(af, bf, C, 0, 0, 0);
#pragma unroll
        for (int rr = 0; rr < 4; ++rr)
          dst[(grp * 4 + rr) * 100 + kk * 32 + h] = o[rr];
      }
    }
  }
  // ---- in-block fc1: R for rows [j0, j0+10) (half=0, +b1), wave 0 only ----
  if (w == 0) {
    int node  = j0 + lm;
    int nodec = node < NV ? node : NV - 1;
    s16x8 af = {0, 0, 0, 0, 0, 0, 0, 0};
    if (grp < 2) {
      const float4* ip = reinterpret_cast<const float4*>(inputs) + (b * NV + nodec) * 4 + grp * 2;
      float4 x0 = ip[0], x1 = ip[1];
      union { unsigned int u[4]; s16x8 v; } U;
      U.u[0] = cvtpk(x0.x, x0.y); U.u[1] = cvtpk(x0.z, x0.w);
      U.u[2] = cvtpk(x1.x, x1.y); U.u[3] = cvtpk(x1.z, x1.w);
      af = U.v;
    }
#pragma unroll
    for (int kk = 0; kk < 3; ++kk) {
#pragma unroll
      for (int nt = 0; nt < 2; ++nt) {
        int h = lm + 16 * nt;
        s16x8 bf = *reinterpret_cast<const s16x8*>(W1t + (kk * 32 + h) * 32 + grp * 8);
        float bv = b1[(kk + 1) * 32 + h];
        f32x4 C = f32x4{bv, bv, bv, bv};
        f32x4 o = __builtin_amdgcn_mfma_f32_16x16x32_bf16(af, bf, C, 0, 0, 0);
#pragma unroll
        for (int rr = 0; rr < 4; ++rr) {
          int lr = grp * 4 + rr;
          if (lr < 10) R_lds[lr * 100 + kk * 32 + h] = o[rr];
        }
      }
    }
  }

  // ---- per-wave persistent fragments (global reads, before barrier) ----
  s16x8 Bf[3][2];                 // W2 B-frags
  float cb[3][2];                 // fc2 bias scalars
#pragma unroll
  for (int kk = 0; kk < 3; ++kk)
#pragma unroll
    for (int nt = 0; nt < 2; ++nt) {
      int h = lm + 16 * nt;
      Bf[kk][nt] = *reinterpret_cast<const s16x8*>(W2t + (kk * 32 + h) * 32 + grp * 8);
      cb[kk][nt] = b2[(kk + 1) * 32 + h];
    }
  const unsigned int zero = 0;
  __syncthreads();

  // ---- this wave's S tile -> registers (f32, row == sender within tile) ----
  float Sreg[3][8];
#pragma unroll
  for (int kk = 0; kk < 3; ++kk) {
    const float* Sp = &S_l[w * 1600 + lm * 100 + kk * 32 + grp * 8];
    f32x4 sA = *reinterpret_cast<const f32x4*>(Sp);
    f32x4 sB = *reinterpret_cast<const f32x4*>(Sp + 4);
#pragma unroll
    for (int p = 0; p < 4; ++p) { Sreg[kk][p] = sA[p]; Sreg[kk][4 + p] = sB[p]; }
  }

  // E-slot base for this lane; w==3, grp>0 lanes are entirely dead (>= 52)
  const int sbase = w * 16 + grp * 4;
  const bool dead = sbase > 48;
  const int sb    = dead ? 48 : sbase;
  const int ro    = w * 2;        // per-wave j rotation (de-phase waves)

  // ---- main loop: 10 receivers, rotated start per wave ----
  for (int t = 0; t < 10; ++t) {
    int jl = t + ro; if (jl >= 10) jl -= 10;
    float s0 = 0.f, s1 = 0.f;
#pragma unroll
    for (int kk = 0; kk < 3; ++kk) {
      const float* Rp = &R_lds[jl * 100 + kk * 32 + grp * 8];
      f32x4 rA = *reinterpret_cast<const f32x4*>(Rp);
      f32x4 rB = *reinterpret_cast<const f32x4*>(Rp + 4);
      union { unsigned int u[4]; s16x8 v; } U;
      U.u[0] = pkmax0(cvtpk(Sreg[kk][0] + rA[0], Sreg[kk][1] + rA[1]), zero);
      U.u[1] = pkmax0(cvtpk(Sreg[kk][2] + rA[2], Sreg[kk][3] + rA[3]), zero);
      U.u[2] = pkmax0(cvtpk(Sreg[kk][4] + rB[0], Sreg[kk][5] + rB[1]), zero);
      U.u[3] = pkmax0(cvtpk(Sreg[kk][6] + rB[2], Sreg[kk][7] + rB[3]), zero);
      f32x4 C0 = f32x4{cb[kk][0], cb[kk][0], cb[kk][0], cb[kk][0]};
      f32x4 C1 = f32x4{cb[kk][1], cb[kk][1], cb[kk][1], cb[kk][1]};
      f32x4 a0 = __builtin_amdgcn_mfma_f32_16x16x32_bf16(U.v, Bf[kk][0], C0, 0, 0, 0);
      f32x4 a1 = __builtin_amdgcn_mfma_f32_16x16x32_bf16(U.v, Bf[kk][1], C1, 0, 0, 0);
      f32x4 ev = *reinterpret_cast<const f32x4*>(&E_lds[jl * 156 + kk * 52 + sb]);
      if (dead) ev = f32x4{0.f, 0.f, 0.f, 0.f};
#pragma unroll
      for (int rr = 0; rr < 4; ++rr) {
        s0 = fmaf(fmaxf(a0[rr], 0.f), ev[rr], s0);
        s1 = fmaf(fmaxf(a1[rr], 0.f), ev[rr], s1);
      }
    }
    s0 += __shfl_xor(s0, 16, 64); s0 += __shfl_xor(s0, 32, 64);
    s1 += __shfl_xor(s1, 16, 64); s1 += __shfl_xor(s1, 32, 64);
    if (l < 16)      atomicAdd(&agg_l[jl * 32 + lm], s0);
    else if (l < 32) atomicAdd(&agg_l[jl * 32 + 16 + lm], s1);
  }
  __syncthreads();
  for (int x = tid; x < 320; x += 256) agg[b * (NV * 32) + j0 * 32 + x] = agg_l[x];
}

// ---------------- Kernel 3: output MLP (fc1 -> fc2 -> mu), LDS-staged B ------
__global__ void __launch_bounds__(256, 3)
k_out(const float* __restrict__ inputs, const float* __restrict__ agg,
      const unsigned short* __restrict__ Wt1sw, const float* __restrict__ bo1,
      const unsigned short* __restrict__ Wt2sw, const float* __restrict__ bo2,
      const unsigned short* __restrict__ Wtmusw, const float* __restrict__ bmu,
      float* __restrict__ out) {
  __shared__ unsigned short aug[64 * 72];
  __shared__ unsigned short P1[64 * 264];
  __shared__ __align__(16) unsigned short WB[16384];

  const int tid = threadIdx.x;
  const int w   = tid >> 6;
  const int l   = tid & 63;
  const int grp = l >> 4;
  const int lm  = l & 15;
  const int gr0 = blockIdx.x * 64;
  const int xo  = (lm & 7) << 3;

  {
    int row = tid >> 2, q = tid & 3;
    int gr = gr0 + row;
    float4 iv = reinterpret_cast<const float4*>(inputs)[gr * 4 + q];
    uint2 u0; u0.x = pk2(iv.x, iv.y); u0.y = pk2(iv.z, iv.w);
    *reinterpret_cast<uint2*>(&aug[row * 72 + q * 4]) = u0;
    float4 a0 = reinterpret_cast<const float4*>(agg)[gr * 8 + q * 2];
    float4 a1 = reinterpret_cast<const float4*>(agg)[gr * 8 + q * 2 + 1];
    uint4 u1; u1.x = pk2(a0.x, a0.y); u1.y = pk2(a0.z, a0.w);
    u1.z = pk2(a1.x, a1.y); u1.w = pk2(a1.z, a1.w);
    *reinterpret_cast<uint4*>(&aug[row * 72 + 16 + q * 8]) = u1;
    uint2 uz; uz.x = 0u; uz.y = 0u;
    *reinterpret_cast<uint2*>(&aug[row * 72 + 48 + q * 4]) = uz;
  }
  {
    const uint4* src = reinterpret_cast<const uint4*>(Wt1sw);
    for (int i = tid; i < 2048; i += 256) reinterpret_cast<uint4*>(WB)[i] = src[i];
  }
  __syncthreads();

  const int rowA  = 16 * w + lm;
  const int kgrp  = grp * 8;
  const int rbase = 16 * w + grp * 4;

  f32x4 acc1[16];
#pragma unroll
  for (int nt = 0; nt < 16; ++nt) acc1[nt] = f32x4{0.f, 0.f, 0.f, 0.f};
#pragma unroll
  for (int kc = 0; kc < 2; ++kc) {
    s16x8 af = *reinterpret_cast<const s16x8*>(&aug[rowA * 72 + kc * 32 + kgrp]);
#pragma unroll
    for (int nt = 0; nt < 16; ++nt) {
      int n = lm + 16 * nt;
      s16x8 bf = *reinterpret_cast<const s16x8*>(&WB[n * 64 + ((kc * 32 + kgrp) ^ xo)]);
      acc1[nt] = __builtin_amdgcn_mfma_f32_16x16x32_bf16(af, bf, acc1[nt], 0, 0, 0);
    }
  }
#pragma unroll
  for (int nt = 0; nt < 16; ++nt) {
    int n = lm + 16 * nt;
    float bias = bo1[n];
#pragma unroll
    for (int rr = 0; rr < 4; ++rr) {
      float v = acc1[nt][rr] + bias; v = v > 0.f ? v : 0.f;
      P1[(rbase + rr) * 264 + n] = f2bf(v);
    }
  }
  __syncthreads();

  f32x4 acc2[16];
#pragma unroll
  for (int nt = 0; nt < 16; ++nt) acc2[nt] = f32x4{0.f, 0.f, 0.f, 0.f};
  for (int c = 0; c < 4; ++c) {
    const uint4* src = reinterpret_cast<const uint4*>(Wt2sw + c * 16384);
    for (int i = tid; i < 2048; i += 256) reinterpret_cast<uint4*>(WB)[i] = src[i];
    __syncthreads();
#pragma unroll
    for (int kcl = 0; kcl < 2; ++kcl) {
      int kc = c * 2 + kcl;
      s16x8 af = *reinterpret_cast<const s16x8*>(&P1[rowA * 264 + kc * 32 + kgrp]);
#pragma unroll
      for (int nt = 0; nt < 16; ++nt) {
        int n = lm + 16 * nt;
        s16x8 bf = *reinterpret_cast<const s16x8*>(&WB[n * 64 + ((kcl * 32 + kgrp) ^ xo)]);
        acc2[nt] = __builtin_amdgcn_mfma_f32_16x16x32_bf16(af, bf, acc2[nt], 0, 0, 0);
      }
    }
    __syncthreads();
  }
#pragma unroll
  for (int nt = 0; nt < 16; ++nt) {
    int n = lm + 16 * nt;
    float bias = bo2[n];
#pragma unroll
    for (int rr = 0; rr < 4; ++rr) {
      float v = acc2[nt][rr] + bias; v = v > 0.f ? v : 0.f;
      out[PRED_OFF + (gr0 + rbase + rr) * 256 + n] = v;
      P1[(rbase + rr) * 264 + n] = f2bf(v);
    }
  }

  {
    const uint4* src = reinterpret_cast<const uint4*>(Wtmusw);
    for (int i = tid; i < 512; i += 256) reinterpret_cast<uint4*>(WB)[i] = src[i];
  }
  __syncthreads();
  f32x4 accm = {0.f, 0.f, 0.f, 0.f};
#pragma unroll
  for (int kc = 0; kc < 8; ++kc) {
    s16x8 af = *reinterpret_cast<const s16x8*>(&P1[rowA * 264 + kc * 32 + kgrp]);
    s16x8 bf = *reinterpret_cast<const s16x8*>(&WB[lm * 256 + ((kc * 32 + kgrp) ^ xo)]);
    accm = __builtin_amdgcn_mfma_f32_16x16x32_bf16(af, bf, accm, 0, 0, 0);
  }
  {
    float bias = bmu[lm];
#pragma unroll
    for (int rr = 0; rr < 4; ++rr) {
      out[(gr0 + rbase + rr) * 16 + lm] = accm[rr] + bias;
    }
  }
}

extern "C" void kernel_launch(void* const* d_in, const int* in_sizes, int n_in,
                              void* d_out, int out_size, void* d_ws, size_t ws_size,
                              hipStream_t stream) {
  const float* inputs = (const float*)d_in[0];
  const float* edges  = (const float*)d_in[1];
  const float* w1     = (const float*)d_in[2];
  const float* b1     = (const float*)d_in[3];
  const float* w2     = (const float*)d_in[4];
  const float* b2     = (const float*)d_in[5];
  const float* wo1    = (const float*)d_in[6];
  const float* bo1    = (const float*)d_in[7];
  const float* wo2    = (const float*)d_in[8];
  const float* bo2    = (const float*)d_in[9];
  const float* wmu    = (const float*)d_in[10];
  const float* bmu    = (const float*)d_in[11];
  float* out = (float*)d_out;

  char* ws = (char*)d_ws;
  float*          agg    = (float*)(ws + 0);
  unsigned short* W2t    = (unsigned short*)(ws + 3276800);
  unsigned short* W1t    = (unsigned short*)(ws + 3282944);
  unsigned short* Wt1sw  = (unsigned short*)(ws + 3295232);
  unsigned short* Wt2sw  = (unsigned short*)(ws + 3328000);
  unsigned short* Wtmusw = (unsigned short*)(ws + 3459072);

  k_tr<<<372, 256, 0, stream>>>(w1, w2, wo1, wo2, wmu, W2t, W1t, Wt1sw, Wt2sw, Wtmusw);
  k_msg<<<dim3(512, 5), 256, 0, stream>>>(inputs, edges, b1, b2, W1t, W2t, agg);
  k_out<<<400, 256, 0, stream>>>(inputs, agg, Wt1sw, bo1, Wt2sw, bo2, Wtmusw, bmu, out);
}

// Round 10
// 70.334 us; speedup vs baseline: 2.8781x; 1.0080x over previous
//
#include <hip/hip_runtime.h>
#include <hip/hip_bf16.h>

#define BATCHN 512
#define NV 50
#define NE 2450
#define INSZ 16
#define MH 32
#define NH 256

typedef short s16x8 __attribute__((ext_vector_type(8)));
typedef float f32x4 __attribute__((ext_vector_type(4)));

#define PRED_OFF (BATCHN * NV * INSZ)   // 409600

// ---- ws layout (bytes) ----
// agg    f32 [B][V][32]      : 0        .. 3276800
// W2t    bf16 [3][32][32]    : 3276800  .. 3282944
// W1t    bf16 [2][3][32][32] : 3282944  .. 3295232
// Wt1sw  bf16 16384          : 3295232  .. 3328000
// Wt2sw  bf16 65536          : 3328000  .. 3459072
// Wtmusw bf16 4096           : 3459072  .. 3467264

__device__ __forceinline__ unsigned short f2bf(float x) {
  unsigned int u = __float_as_uint(x);
  unsigned int r = (u + 0x7fffu + ((u >> 16) & 1u)) >> 16;  // RTNE
  return (unsigned short)r;
}
__device__ __forceinline__ unsigned int pk2(float a, float b) {
  return (unsigned int)f2bf(a) | ((unsigned int)f2bf(b) << 16);
}
__device__ __forceinline__ unsigned int cvtpk(float lo, float hi) {
  unsigned int r;
  asm("v_cvt_pk_bf16_f32 %0, %1, %2" : "=v"(r) : "v"(lo), "v"(hi));
  return r;
}
__device__ __forceinline__ unsigned int pkmax0(unsigned int x, unsigned int z) {
  unsigned int r;
  asm("v_pk_max_i16 %0, %1, %2" : "=v"(r) : "v"(x), "v"(z));
  return r;
}

// ---------------- Kernel 1: weight transforms -------------------
__global__ void k_tr(const float* __restrict__ w1, const float* __restrict__ w2,
                     const float* __restrict__ wo1, const float* __restrict__ wo2,
                     const float* __restrict__ wmu,
                     unsigned short* __restrict__ W2t, unsigned short* __restrict__ W1t,
                     unsigned short* __restrict__ Wt1sw, unsigned short* __restrict__ Wt2sw,
                     unsigned short* __restrict__ Wtmusw) {
  int idx = blockIdx.x * 256 + threadIdx.x;
  if (idx < 3072) {                      // W2t[kk][h][c] = w2[(kk+1)*32 + c][h]
    int c = idx & 31, h = (idx >> 5) & 31, kk = idx >> 10;
    W2t[idx] = f2bf(w2[((kk + 1) * 32 + c) * 32 + h]);
  } else if (idx < 9216) {               // W1t[half][kk][n][k]
    int j = idx - 3072;
    int k = j & 31, n = (j >> 5) & 31, kk = (j >> 10) % 3, half = j / 3072;
    W1t[j] = f2bf(k < 16 ? w1[((kk + 1) * 32 + half * 16 + k) * 32 + n] : 0.f);
  } else if (idx < 9216 + 16384) {       // Wt1sw
    int j = idx - 9216; int n = j & 255, kl = j >> 8;
    float v = kl < 48 ? wo1[kl * 256 + n] : 0.f;
    Wt1sw[n * 64 + (kl ^ ((n & 7) << 3))] = f2bf(v);
  } else if (idx < 9216 + 16384 + 65536) { // Wt2sw
    int j = idx - (9216 + 16384);
    int c = j >> 14, r = j & 16383;
    int n = r & 255, kl = r >> 8;
    float v = wo2[(c * 64 + kl) * 256 + n];
    Wt2sw[(c * 256 + n) * 64 + (kl ^ ((n & 7) << 3))] = f2bf(v);
  } else if (idx < 9216 + 16384 + 65536 + 4096) { // Wtmusw
    int j = idx - (9216 + 16384 + 65536);
    int n = j & 15, kl = j >> 4;
    Wtmusw[n * 256 + (kl ^ ((n & 7) << 3))] = f2bf(wmu[kl * 16 + n]);
  }
}

// ---------------- Kernel 2: fused fc1 + messages + scatter (scheme-E) --------
// grid 512 (one block per batch), 512 threads (8 waves). Wave w owns receivers
// j = w, w+8, ...; full S table register-resident (96 VGPR, asm-pinned so the
// compiler cannot rematerialize from LDS — the R6 failure mode). Per wave-j
// LDS traffic: 6 R-b128 + 12 E-b128 + 4 shfl; no atomics; direct global store.
// Slot == sender index; diagonal and slots >= 50 carry E = 0.
__global__ void __launch_bounds__(512, 3)
k_msg(const float* __restrict__ inputs, const float* __restrict__ edges,
      const float* __restrict__ b1, const float* __restrict__ b2,
      const unsigned short* __restrict__ W1t, const unsigned short* __restrict__ W2t,
      float* __restrict__ agg) {
  __shared__ __align__(16) float R_lds[NV * 100];   // f32, stride 100
  __shared__ __align__(16) float S_lds[NV * 100];   // f32, stride 100
  __shared__ __align__(16) float E_lds[NV * 156];   // [j][kk][52 slots]; slot==sender

  const int b   = blockIdx.x;
  const int tid = threadIdx.x;
  const int w   = tid >> 6;       // 0..7
  const int l   = tid & 63;
  const int grp = l >> 4;         // 0..3
  const int lm  = l & 15;

  // ---- stage edge coefficients; slot r IS the sender index (52 slots) ----
  for (int x = tid; x < NV * 52; x += 512) {
    int r = x / 50;               // sender index 0..51
    int j = x - r * 50;           // receiver
    float4 ev = make_float4(0.f, 0.f, 0.f, 0.f);
    if (r < NV && r != j) {
      int e = r * 49 + j - (j > r ? 1 : 0);
      ev = reinterpret_cast<const float4*>(edges)[b * NE + e];
    }
    int base = j * 156 + r;
    E_lds[base]       = ev.y;     // edge types 1..3 only (SKIP_FIRST)
    E_lds[base + 52]  = ev.z;
    E_lds[base + 104] = ev.w;
  }

  // ---- in-block fc1 GEMM: R/S = inputs @ W1 halves (K=16 zero-padded) ----
  {
    const int half = w >> 2;      // 0 = recv weights (R, +b1), 1 = send weights (S)
    const int mt4  = w & 3;       // node tile
    int node  = mt4 * 16 + lm;
    int nodec = node < NV ? node : NV - 1;
    s16x8 af = {0, 0, 0, 0, 0, 0, 0, 0};
    if (grp < 2) {
      const float4* ip = reinterpret_cast<const float4*>(inputs) + (b * NV + nodec) * 4 + grp * 2;
      float4 x0 = ip[0], x1 = ip[1];
      union { unsigned int u[4]; s16x8 v; } U;
      U.u[0] = cvtpk(x0.x, x0.y); U.u[1] = cvtpk(x0.z, x0.w);
      U.u[2] = cvtpk(x1.x, x1.y); U.u[3] = cvtpk(x1.z, x1.w);
      af = U.v;
    }
    float* dst = half ? S_lds : R_lds;
#pragma unroll
    for (int kk = 0; kk < 3; ++kk) {
#pragma unroll
      for (int nt = 0; nt < 2; ++nt) {
        int h = lm + 16 * nt;
        s16x8 bf = *reinterpret_cast<const s16x8*>(W1t + ((half * 3 + kk) * 32 + h) * 32 + grp * 8);
        f32x4 C;
        if (half == 0) { float bv = b1[(kk + 1) * 32 + h]; C = f32x4{bv, bv, bv, bv}; }
        else C = f32x4{0.f, 0.f, 0.f, 0.f};
        f32x4 o = __builtin_amdgcn_mfma_f32_16x16x32_bf16(af, bf, C, 0, 0, 0);
#pragma unroll
        for (int rr = 0; rr < 4; ++rr) {
          int n2 = mt4 * 16 + grp * 4 + rr;
          if (n2 < NV) dst[n2 * 100 + kk * 32 + h] = o[rr];
        }
      }
    }
  }

  // ---- per-wave persistent fragments (global reads, before barrier) ----
  s16x8 Bf[3][2];                 // W2 B-frags (24 VGPR)
  float cb[3][2];                 // fc2 bias scalars
#pragma unroll
  for (int kk = 0; kk < 3; ++kk)
#pragma unroll
    for (int nt = 0; nt < 2; ++nt) {
      int h = lm + 16 * nt;
      Bf[kk][nt] = *reinterpret_cast<const s16x8*>(W2t + (kk * 32 + h) * 32 + grp * 8);
      cb[kk][nt] = b2[(kk + 1) * 32 + h];
    }
  const unsigned int zero = 0;
  __syncthreads();

  // ---- full S table -> registers (row == sender index), PINNED ----
  f32x4 Sr[4][3][2];              // 96 VGPR
#pragma unroll
  for (int mt = 0; mt < 4; ++mt) {
    int srow = mt * 16 + lm;
    int src  = srow < NV ? srow : NV - 1;   // rows >=50 clamped; killed by E=0
#pragma unroll
    for (int kk = 0; kk < 3; ++kk) {
      const float* Sp = &S_lds[src * 100 + kk * 32 + grp * 8];
      Sr[mt][kk][0] = *reinterpret_cast<const f32x4*>(Sp);
      Sr[mt][kk][1] = *reinterpret_cast<const f32x4*>(Sp + 4);
      asm volatile("" : "+v"(Sr[mt][kk][0]));   // pin: no LDS remat
      asm volatile("" : "+v"(Sr[mt][kk][1]));
    }
  }

  // ---- main loop: wave owns receivers j = w, w+8, ... (all senders) ----
  for (int j = w; j < NV; j += 8) {
    float s0 = 0.f, s1 = 0.f;
#pragma unroll
    for (int kk = 0; kk < 3; ++kk) {
      const float* Rp = &R_lds[j * 100 + kk * 32 + grp * 8];
      f32x4 rA = *reinterpret_cast<const f32x4*>(Rp);
      f32x4 rB = *reinterpret_cast<const f32x4*>(Rp + 4);
#pragma unroll
      for (int mt = 0; mt < 4; ++mt) {
        f32x4 sA = Sr[mt][kk][0], sB = Sr[mt][kk][1];
        union { unsigned int u[4]; s16x8 v; } U;
        U.u[0] = pkmax0(cvtpk(sA[0] + rA[0], sA[1] + rA[1]), zero);
        U.u[1] = pkmax0(cvtpk(sA[2] + rA[2], sA[3] + rA[3]), zero);
        U.u[2] = pkmax0(cvtpk(sB[0] + rB[0], sB[1] + rB[1]), zero);
        U.u[3] = pkmax0(cvtpk(sB[2] + rB[2], sB[3] + rB[3]), zero);
        f32x4 C0 = f32x4{cb[kk][0], cb[kk][0], cb[kk][0], cb[kk][0]};
        f32x4 C1 = f32x4{cb[kk][1], cb[kk][1], cb[kk][1], cb[kk][1]};
        f32x4 a0 = __builtin_amdgcn_mfma_f32_16x16x32_bf16(U.v, Bf[kk][0], C0, 0, 0, 0);
        f32x4 a1 = __builtin_amdgcn_mfma_f32_16x16x32_bf16(U.v, Bf[kk][1], C1, 0, 0, 0);
        int sbase = mt * 16 + grp * 4;
        f32x4 ev;
        if (mt < 3) {
          ev = *reinterpret_cast<const f32x4*>(&E_lds[j * 156 + kk * 52 + sbase]);
        } else {
          ev = *reinterpret_cast<const f32x4*>(&E_lds[j * 156 + kk * 52 + 48]);
          if (grp) ev = f32x4{0.f, 0.f, 0.f, 0.f};
        }
#pragma unroll
        for (int rr = 0; rr < 4; ++rr) {
          s0 = fmaf(fmaxf(a0[rr], 0.f), ev[rr], s0);
          s1 = fmaf(fmaxf(a1[rr], 0.f), ev[rr], s1);
        }
      }
    }
    s0 += __shfl_xor(s0, 16, 64); s0 += __shfl_xor(s0, 32, 64);
    s1 += __shfl_xor(s1, 16, 64); s1 += __shfl_xor(s1, 32, 64);
    if (l < 16)      agg[(b * NV + j) * MH + lm] = s0;
    else if (l < 32) agg[(b * NV + j) * MH + 16 + lm] = s1;
  }
}

// ---------------- Kernel 3: output MLP (fc1 -> fc2 -> mu), LDS-staged B ------
__global__ void __launch_bounds__(256, 3)
k_out(const float* __restrict__ inputs, const float* __restrict__ agg,
      const unsigned short* __restrict__ Wt1sw, const float* __restrict__ bo1,
      const unsigned short* __restrict__ Wt2sw, const float* __restrict__ bo2,
      const unsigned short* __restrict__ Wtmusw, const float* __restrict__ bmu,
      float* __restrict__ out) {
  __shared__ unsigned short aug[64 * 72];
  __shared__ unsigned short P1[64 * 264];
  __shared__ __align__(16) unsigned short WB[16384];

  const int tid = threadIdx.x;
  const int w   = tid >> 6;
  const int l   = tid & 63;
  const int grp = l >> 4;
  const int lm  = l & 15;
  const int gr0 = blockIdx.x * 64;
  const int xo  = (lm & 7) << 3;

  {
    int row = tid >> 2, q = tid & 3;
    int gr = gr0 + row;
    float4 iv = reinterpret_cast<const float4*>(inputs)[gr * 4 + q];
    uint2 u0; u0.x = pk2(iv.x, iv.y); u0.y = pk2(iv.z, iv.w);
    *reinterpret_cast<uint2*>(&aug[row * 72 + q * 4]) = u0;
    float4 a0 = reinterpret_cast<const float4*>(agg)[gr * 8 + q * 2];
    float4 a1 = reinterpret_cast<const float4*>(agg)[gr * 8 + q * 2 + 1];
    uint4 u1; u1.x = pk2(a0.x, a0.y); u1.y = pk2(a0.z, a0.w);
    u1.z = pk2(a1.x, a1.y); u1.w = pk2(a1.z, a1.w);
    *reinterpret_cast<uint4*>(&aug[row * 72 + 16 + q * 8]) = u1;
    uint2 uz; uz.x = 0u; uz.y = 0u;
    *reinterpret_cast<uint2*>(&aug[row * 72 + 48 + q * 4]) = uz;
  }
  {
    const uint4* src = reinterpret_cast<const uint4*>(Wt1sw);
    for (int i = tid; i < 2048; i += 256) reinterpret_cast<uint4*>(WB)[i] = src[i];
  }
  __syncthreads();

  const int rowA  = 16 * w + lm;
  const int kgrp  = grp * 8;
  const int rbase = 16 * w + grp * 4;

  f32x4 acc1[16];
#pragma unroll
  for (int nt = 0; nt < 16; ++nt) acc1[nt] = f32x4{0.f, 0.f, 0.f, 0.f};
#pragma unroll
  for (int kc = 0; kc < 2; ++kc) {
    s16x8 af = *reinterpret_cast<const s16x8*>(&aug[rowA * 72 + kc * 32 + kgrp]);
#pragma unroll
    for (int nt = 0; nt < 16; ++nt) {
      int n = lm + 16 * nt;
      s16x8 bf = *reinterpret_cast<const s16x8*>(&WB[n * 64 + ((kc * 32 + kgrp) ^ xo)]);
      acc1[nt] = __builtin_amdgcn_mfma_f32_16x16x32_bf16(af, bf, acc1[nt], 0, 0, 0);
    }
  }
#pragma unroll
  for (int nt = 0; nt < 16; ++nt) {
    int n = lm + 16 * nt;
    float bias = bo1[n];
#pragma unroll
    for (int rr = 0; rr < 4; ++rr) {
      float v = acc1[nt][rr] + bias; v = v > 0.f ? v : 0.f;
      P1[(rbase + rr) * 264 + n] = f2bf(v);
    }
  }
  __syncthreads();

  f32x4 acc2[16];
#pragma unroll
  for (int nt = 0; nt < 16; ++nt) acc2[nt] = f32x4{0.f, 0.f, 0.f, 0.f};
  for (int c = 0; c < 4; ++c) {
    const uint4* src = reinterpret_cast<const uint4*>(Wt2sw + c * 16384);
    for (int i = tid; i < 2048; i += 256) reinterpret_cast<uint4*>(WB)[i] = src[i];
    __syncthreads();
#pragma unroll
    for (int kcl = 0; kcl < 2; ++kcl) {
      int kc = c * 2 + kcl;
      s16x8 af = *reinterpret_cast<const s16x8*>(&P1[rowA * 264 + kc * 32 + kgrp]);
#pragma unroll
      for (int nt = 0; nt < 16; ++nt) {
        int n = lm + 16 * nt;
        s16x8 bf = *reinterpret_cast<const s16x8*>(&WB[n * 64 + ((kcl * 32 + kgrp) ^ xo)]);
        acc2[nt] = __builtin_amdgcn_mfma_f32_16x16x32_bf16(af, bf, acc2[nt], 0, 0, 0);
      }
    }
    __syncthreads();
  }
#pragma unroll
  for (int nt = 0; nt < 16; ++nt) {
    int n = lm + 16 * nt;
    float bias = bo2[n];
#pragma unroll
    for (int rr = 0; rr < 4; ++rr) {
      float v = acc2[nt][rr] + bias; v = v > 0.f ? v : 0.f;
      out[PRED_OFF + (gr0 + rbase + rr) * 256 + n] = v;
      P1[(rbase + rr) * 264 + n] = f2bf(v);
    }
  }

  {
    const uint4* src = reinterpret_cast<const uint4*>(Wtmusw);
    for (int i = tid; i < 512; i += 256) reinterpret_cast<uint4*>(WB)[i] = src[i];
  }
  __syncthreads();
  f32x4 accm = {0.f, 0.f, 0.f, 0.f};
#pragma unroll
  for (int kc = 0; kc < 8; ++kc) {
    s16x8 af = *reinterpret_cast<const s16x8*>(&P1[rowA * 264 + kc * 32 + kgrp]);
    s16x8 bf = *reinterpret_cast<const s16x8*>(&WB[lm * 256 + ((kc * 32 + kgrp) ^ xo)]);
    accm = __builtin_amdgcn_mfma_f32_16x16x32_bf16(af, bf, accm, 0, 0, 0);
  }
  {
    float bias = bmu[lm];
#pragma unroll
    for (int rr = 0; rr < 4; ++rr) {
      out[(gr0 + rbase + rr) * 16 + lm] = accm[rr] + bias;
    }
  }
}

extern "C" void kernel_launch(void* const* d_in, const int* in_sizes, int n_in,
                              void* d_out, int out_size, void* d_ws, size_t ws_size,
                              hipStream_t stream) {
  const float* inputs = (const float*)d_in[0];
  const float* edges  = (const float*)d_in[1];
  const float* w1     = (const float*)d_in[2];
  const float* b1     = (const float*)d_in[3];
  const float* w2     = (const float*)d_in[4];
  const float* b2     = (const float*)d_in[5];
  const float* wo1    = (const float*)d_in[6];
  const float* bo1    = (const float*)d_in[7];
  const float* wo2    = (const float*)d_in[8];
  const float* bo2    = (const float*)d_in[9];
  const float* wmu    = (const float*)d_in[10];
  const float* bmu    = (const float*)d_in[11];
  float* out = (float*)d_out;

  char* ws = (char*)d_ws;
  float*          agg    = (float*)(ws + 0);
  unsigned short* W2t    = (unsigned short*)(ws + 3276800);
  unsigned short* W1t    = (unsigned short*)(ws + 3282944);
  unsigned short* Wt1sw  = (unsigned short*)(ws + 3295232);
  unsigned short* Wt2sw  = (unsigned short*)(ws + 3328000);
  unsigned short* Wtmusw = (unsigned short*)(ws + 3459072);

  k_tr<<<372, 256, 0, stream>>>(w1, w2, wo1, wo2, wmu, W2t, W1t, Wt1sw, Wt2sw, Wtmusw);
  k_msg<<<512, 512, 0, stream>>>(inputs, edges, b1, b2, W1t, W2t, agg);
  k_out<<<400, 256, 0, stream>>>(inputs, agg, Wt1sw, bo1, Wt2sw, bo2, Wtmusw, bmu, out);
}

// Round 11
// 59.594 us; speedup vs baseline: 3.3968x; 1.1802x over previous
//
#include <hip/hip_runtime.h>
#include <hip/hip_bf16.h>

#define BATCHN 512
#define NV 50
#define NE 2450
#define INSZ 16
#define MH 32
#define NH 256

typedef short s16x8 __attribute__((ext_vector_type(8)));
typedef float f32x4 __attribute__((ext_vector_type(4)));
typedef float f32x2 __attribute__((ext_vector_type(2)));

#define PRED_OFF (BATCHN * NV * INSZ)   // 409600

// ---- ws layout (bytes) ----
// agg    f32 [B][V][32]      : 0        .. 3276800
// W2t    bf16 [3][32][32]    : 3276800  .. 3282944
// W1t    bf16 [2][3][32][32] : 3282944  .. 3295232
// Wt1sw  bf16 16384          : 3295232  .. 3328000
// Wt2sw  bf16 65536          : 3328000  .. 3459072
// Wtmusw bf16 4096           : 3459072  .. 3467264

__device__ __forceinline__ unsigned short f2bf(float x) {
  unsigned int u = __float_as_uint(x);
  unsigned int r = (u + 0x7fffu + ((u >> 16) & 1u)) >> 16;  // RTNE
  return (unsigned short)r;
}
__device__ __forceinline__ unsigned int pk2(float a, float b) {
  return (unsigned int)f2bf(a) | ((unsigned int)f2bf(b) << 16);
}
__device__ __forceinline__ unsigned int cvtpk(float lo, float hi) {
  unsigned int r;
  asm("v_cvt_pk_bf16_f32 %0, %1, %2" : "=v"(r) : "v"(lo), "v"(hi));
  return r;
}
__device__ __forceinline__ unsigned int pkmax0(unsigned int x, unsigned int z) {
  unsigned int r;
  asm("v_pk_max_i16 %0, %1, %2" : "=v"(r) : "v"(x), "v"(z));
  return r;
}

// ---------------- Kernel 1: weight transforms -------------------
__global__ void k_tr(const float* __restrict__ w1, const float* __restrict__ w2,
                     const float* __restrict__ wo1, const float* __restrict__ wo2,
                     const float* __restrict__ wmu,
                     unsigned short* __restrict__ W2t, unsigned short* __restrict__ W1t,
                     unsigned short* __restrict__ Wt1sw, unsigned short* __restrict__ Wt2sw,
                     unsigned short* __restrict__ Wtmusw) {
  int idx = blockIdx.x * 256 + threadIdx.x;
  if (idx < 3072) {                      // W2t[kk][h][c] = w2[(kk+1)*32 + c][h]
    int c = idx & 31, h = (idx >> 5) & 31, kk = idx >> 10;
    W2t[idx] = f2bf(w2[((kk + 1) * 32 + c) * 32 + h]);
  } else if (idx < 9216) {               // W1t[half][kk][n][k]
    int j = idx - 3072;
    int k = j & 31, n = (j >> 5) & 31, kk = (j >> 10) % 3, half = j / 3072;
    W1t[j] = f2bf(k < 16 ? w1[((kk + 1) * 32 + half * 16 + k) * 32 + n] : 0.f);
  } else if (idx < 9216 + 16384) {       // Wt1sw
    int j = idx - 9216; int n = j & 255, kl = j >> 8;
    float v = kl < 48 ? wo1[kl * 256 + n] : 0.f;
    Wt1sw[n * 64 + (kl ^ ((n & 7) << 3))] = f2bf(v);
  } else if (idx < 9216 + 16384 + 65536) { // Wt2sw
    int j = idx - (9216 + 16384);
    int c = j >> 14, r = j & 16383;
    int n = r & 255, kl = r >> 8;
    float v = wo2[(c * 64 + kl) * 256 + n];
    Wt2sw[(c * 256 + n) * 64 + (kl ^ ((n & 7) << 3))] = f2bf(v);
  } else if (idx < 9216 + 16384 + 65536 + 4096) { // Wtmusw
    int j = idx - (9216 + 16384 + 65536);
    int n = j & 15, kl = j >> 4;
    Wtmusw[n * 256 + (kl ^ ((n & 7) << 3))] = f2bf(wmu[kl * 16 + n]);
  }
}

// ---------------- Kernel 2: fused fc1 + messages (scheme-F) -------------------
// grid 512, 512 thr (8 waves). RECEIVERS are the MFMA M-dim: wave w =
// (jt = w&3: rows j = jt*16..+15; ih = w>>2: sender parity). Per sender i:
// A[j,ch] = relu(Rreg[j] + S_broadcast[i]), D = A @ W2k (+b2 via MFMA C),
// acc[j,hout] += E[j,i,kk] * relu(D). Lanes own (j,hout) accumulators over the
// whole i loop: NO shfl reduction, NO atomics, no per-j tail. The two parity
// waves combine once via LDS (overlaid on dead R_lds). Diagonal and pad
// j-slots carry E = 0.
__global__ void __launch_bounds__(512, 4)
k_msg(const float* __restrict__ inputs, const float* __restrict__ edges,
      const float* __restrict__ b1, const float* __restrict__ b2,
      const unsigned short* __restrict__ W1t, const unsigned short* __restrict__ W2t,
      float* __restrict__ agg) {
  __shared__ __align__(16) float S_lds[NV * 100];   // f32, stride 100
  __shared__ __align__(16) float R_lds[NV * 100];   // f32; reused as comb buffer
  __shared__ __align__(16) float E_lds[NV * 156];   // [i][kk][52 j-slots]

  const int b   = blockIdx.x;
  const int tid = threadIdx.x;
  const int w   = tid >> 6;       // 0..7
  const int l   = tid & 63;
  const int grp = l >> 4;         // 0..3
  const int lm  = l & 15;
  const int jt  = w & 3;          // receiver tile
  const int ih  = w >> 2;         // sender parity

  // ---- stage E: E_lds[i][kk][j] = edges[b, e(i->j), kk+1]; diag/pad = 0 ----
  for (int x = tid; x < NV * 52; x += 512) {
    int i  = x / 52;
    int js = x - i * 52;
    float4 ev = make_float4(0.f, 0.f, 0.f, 0.f);
    if (js < NV && js != i) {
      int e = i * 49 + js - (js > i ? 1 : 0);
      ev = reinterpret_cast<const float4*>(edges)[b * NE + e];
    }
    int base = i * 156 + js;
    E_lds[base]       = ev.y;     // edge types 1..3 only (SKIP_FIRST)
    E_lds[base + 52]  = ev.z;
    E_lds[base + 104] = ev.w;
  }

  // ---- in-block fc1 GEMM: R/S = inputs @ W1 halves (K=16 zero-padded) ----
  {
    const int half = w >> 2;      // 0 = recv weights (R, +b1), 1 = send weights (S)
    const int mt4  = w & 3;       // node tile
    int node  = mt4 * 16 + lm;
    int nodec = node < NV ? node : NV - 1;
    s16x8 af = {0, 0, 0, 0, 0, 0, 0, 0};
    if (grp < 2) {
      const float4* ip = reinterpret_cast<const float4*>(inputs) + (b * NV + nodec) * 4 + grp * 2;
      float4 x0 = ip[0], x1 = ip[1];
      union { unsigned int u[4]; s16x8 v; } U;
      U.u[0] = cvtpk(x0.x, x0.y); U.u[1] = cvtpk(x0.z, x0.w);
      U.u[2] = cvtpk(x1.x, x1.y); U.u[3] = cvtpk(x1.z, x1.w);
      af = U.v;
    }
    float* dst = half ? S_lds : R_lds;
#pragma unroll
    for (int kk = 0; kk < 3; ++kk) {
#pragma unroll
      for (int nt = 0; nt < 2; ++nt) {
        int h = lm + 16 * nt;
        s16x8 bf = *reinterpret_cast<const s16x8*>(W1t + ((half * 3 + kk) * 32 + h) * 32 + grp * 8);
        f32x4 C;
        if (half == 0) { float bv = b1[(kk + 1) * 32 + h]; C = f32x4{bv, bv, bv, bv}; }
        else C = f32x4{0.f, 0.f, 0.f, 0.f};
        f32x4 o = __builtin_amdgcn_mfma_f32_16x16x32_bf16(af, bf, C, 0, 0, 0);
#pragma unroll
        for (int rr = 0; rr < 4; ++rr) {
          int n2 = mt4 * 16 + grp * 4 + rr;
          if (n2 < NV) dst[n2 * 100 + kk * 32 + h] = o[rr];
        }
      }
    }
  }

  // ---- per-wave persistent fragments (global reads, before barrier) ----
  s16x8 Bf[3][2];                 // W2 B-frags
  f32x4 Cb[3][2];                 // fc2 bias as MFMA C operand
#pragma unroll
  for (int kk = 0; kk < 3; ++kk)
#pragma unroll
    for (int nt = 0; nt < 2; ++nt) {
      int h = lm + 16 * nt;
      Bf[kk][nt] = *reinterpret_cast<const s16x8*>(W2t + (kk * 32 + h) * 32 + grp * 8);
      float bv = b2[(kk + 1) * 32 + h];
      Cb[kk][nt] = f32x4{bv, bv, bv, bv};
    }
  const unsigned int zero = 0;
  __syncthreads();

  // ---- Rreg: this wave's 16 receiver rows (A row = lm) ----
  float Rreg[3][8];
  {
    int jrow = jt * 16 + lm;
    int jr   = jrow < NV ? jrow : NV - 1;   // dead rows killed by E=0 + store mask
#pragma unroll
    for (int kk = 0; kk < 3; ++kk) {
      const float* Rp = &R_lds[jr * 100 + kk * 32 + grp * 8];
      f32x4 rA = *reinterpret_cast<const f32x4*>(Rp);
      f32x4 rB = *reinterpret_cast<const f32x4*>(Rp + 4);
#pragma unroll
      for (int p = 0; p < 4; ++p) { Rreg[kk][p] = rA[p]; Rreg[kk][4 + p] = rB[p]; }
    }
  }
  __syncthreads();   // R_lds dead beyond here (comb buffer overlays it)

  // E-slot base for this lane's D rows (j = jt*16 + grp*4 + rr)
  const int slot0 = jt * 16 + grp * 4;
  const bool dead = slot0 > 48;             // only jt==3, grp>0
  const int slot  = dead ? 48 : slot0;

  f32x4 acc0 = {0.f, 0.f, 0.f, 0.f};
  f32x4 acc1 = {0.f, 0.f, 0.f, 0.f};

  // ---- main loop over senders (parity-split across the 2 waves per jt) ----
  for (int i = ih; i < NV; i += 2) {
    const float* Eb = &E_lds[i * 156 + slot];
#pragma unroll
    for (int kk = 0; kk < 3; ++kk) {
      const float* Sp = &S_lds[i * 100 + kk * 32 + grp * 8];
      f32x4 sA = *reinterpret_cast<const f32x4*>(Sp);       // broadcast reads
      f32x4 sB = *reinterpret_cast<const f32x4*>(Sp + 4);
      union { unsigned int u[4]; s16x8 v; } U;
      U.u[0] = pkmax0(cvtpk(Rreg[kk][0] + sA[0], Rreg[kk][1] + sA[1]), zero);
      U.u[1] = pkmax0(cvtpk(Rreg[kk][2] + sA[2], Rreg[kk][3] + sA[3]), zero);
      U.u[2] = pkmax0(cvtpk(Rreg[kk][4] + sB[0], Rreg[kk][5] + sB[1]), zero);
      U.u[3] = pkmax0(cvtpk(Rreg[kk][6] + sB[2], Rreg[kk][7] + sB[3]), zero);
      f32x4 d0 = __builtin_amdgcn_mfma_f32_16x16x32_bf16(U.v, Bf[kk][0], Cb[kk][0], 0, 0, 0);
      f32x4 d1 = __builtin_amdgcn_mfma_f32_16x16x32_bf16(U.v, Bf[kk][1], Cb[kk][1], 0, 0, 0);
      f32x4 ev = *reinterpret_cast<const f32x4*>(Eb + kk * 52);
      if (dead) ev = f32x4{0.f, 0.f, 0.f, 0.f};
#pragma unroll
      for (int rr = 0; rr < 4; ++rr) {
        acc0[rr] = fmaf(fmaxf(d0[rr], 0.f), ev[rr], acc0[rr]);
        acc1[rr] = fmaf(fmaxf(d1[rr], 0.f), ev[rr], acc1[rr]);
      }
    }
  }

  // ---- combine the two parity waves; store ----
  float* comb = R_lds;            // overlaid
  if (ih == 1) {
    int cbase = (jt * 64 + l) * 10;         // stride 10 f32 (8B-aligned b64s)
    *reinterpret_cast<f32x2*>(&comb[cbase])     = f32x2{acc0[0], acc0[1]};
    *reinterpret_cast<f32x2*>(&comb[cbase + 2]) = f32x2{acc0[2], acc0[3]};
    *reinterpret_cast<f32x2*>(&comb[cbase + 4]) = f32x2{acc1[0], acc1[1]};
    *reinterpret_cast<f32x2*>(&comb[cbase + 6]) = f32x2{acc1[2], acc1[3]};
  }
  __syncthreads();
  if (ih == 0) {
    int cbase = (jt * 64 + l) * 10;
    f32x2 c0 = *reinterpret_cast<const f32x2*>(&comb[cbase]);
    f32x2 c1 = *reinterpret_cast<const f32x2*>(&comb[cbase + 2]);
    f32x2 c2 = *reinterpret_cast<const f32x2*>(&comb[cbase + 4]);
    f32x2 c3 = *reinterpret_cast<const f32x2*>(&comb[cbase + 6]);
    acc0[0] += c0[0]; acc0[1] += c0[1]; acc0[2] += c1[0]; acc0[3] += c1[1];
    acc1[0] += c2[0]; acc1[1] += c2[1]; acc1[2] += c3[0]; acc1[3] += c3[1];
#pragma unroll
    for (int rr = 0; rr < 4; ++rr) {
      int j = jt * 16 + grp * 4 + rr;       // D row = (l>>4)*4 + rr
      if (j < NV) {
        agg[(b * NV + j) * MH + lm]      = acc0[rr];
        agg[(b * NV + j) * MH + 16 + lm] = acc1[rr];
      }
    }
  }
}

// ---------------- Kernel 3: output MLP (fc1 -> fc2 -> mu), LDS-staged B ------
__global__ void __launch_bounds__(256, 3)
k_out(const float* __restrict__ inputs, const float* __restrict__ agg,
      const unsigned short* __restrict__ Wt1sw, const float* __restrict__ bo1,
      const unsigned short* __restrict__ Wt2sw, const float* __restrict__ bo2,
      const unsigned short* __restrict__ Wtmusw, const float* __restrict__ bmu,
      float* __restrict__ out) {
  __shared__ unsigned short aug[64 * 72];
  __shared__ unsigned short P1[64 * 264];
  __shared__ __align__(16) unsigned short WB[16384];

  const int tid = threadIdx.x;
  const int w   = tid >> 6;
  const int l   = tid & 63;
  const int grp = l >> 4;
  const int lm  = l & 15;
  const int gr0 = blockIdx.x * 64;
  const int xo  = (lm & 7) << 3;

  {
    int row = tid >> 2, q = tid & 3;
    int gr = gr0 + row;
    float4 iv = reinterpret_cast<const float4*>(inputs)[gr * 4 + q];
    uint2 u0; u0.x = pk2(iv.x, iv.y); u0.y = pk2(iv.z, iv.w);
    *reinterpret_cast<uint2*>(&aug[row * 72 + q * 4]) = u0;
    float4 a0 = reinterpret_cast<const float4*>(agg)[gr * 8 + q * 2];
    float4 a1 = reinterpret_cast<const float4*>(agg)[gr * 8 + q * 2 + 1];
    uint4 u1; u1.x = pk2(a0.x, a0.y); u1.y = pk2(a0.z, a0.w);
    u1.z = pk2(a1.x, a1.y); u1.w = pk2(a1.z, a1.w);
    *reinterpret_cast<uint4*>(&aug[row * 72 + 16 + q * 8]) = u1;
    uint2 uz; uz.x = 0u; uz.y = 0u;
    *reinterpret_cast<uint2*>(&aug[row * 72 + 48 + q * 4]) = uz;
  }
  {
    const uint4* src = reinterpret_cast<const uint4*>(Wt1sw);
    for (int i = tid; i < 2048; i += 256) reinterpret_cast<uint4*>(WB)[i] = src[i];
  }
  __syncthreads();

  const int rowA  = 16 * w + lm;
  const int kgrp  = grp * 8;
  const int rbase = 16 * w + grp * 4;

  f32x4 acc1[16];
#pragma unroll
  for (int nt = 0; nt < 16; ++nt) acc1[nt] = f32x4{0.f, 0.f, 0.f, 0.f};
#pragma unroll
  for (int kc = 0; kc < 2; ++kc) {
    s16x8 af = *reinterpret_cast<const s16x8*>(&aug[rowA * 72 + kc * 32 + kgrp]);
#pragma unroll
    for (int nt = 0; nt < 16; ++nt) {
      int n = lm + 16 * nt;
      s16x8 bf = *reinterpret_cast<const s16x8*>(&WB[n * 64 + ((kc * 32 + kgrp) ^ xo)]);
      acc1[nt] = __builtin_amdgcn_mfma_f32_16x16x32_bf16(af, bf, acc1[nt], 0, 0, 0);
    }
  }
#pragma unroll
  for (int nt = 0; nt < 16; ++nt) {
    int n = lm + 16 * nt;
    float bias = bo1[n];
#pragma unroll
    for (int rr = 0; rr < 4; ++rr) {
      float v = acc1[nt][rr] + bias; v = v > 0.f ? v : 0.f;
      P1[(rbase + rr) * 264 + n] = f2bf(v);
    }
  }
  __syncthreads();

  f32x4 acc2[16];
#pragma unroll
  for (int nt = 0; nt < 16; ++nt) acc2[nt] = f32x4{0.f, 0.f, 0.f, 0.f};
  for (int c = 0; c < 4; ++c) {
    const uint4* src = reinterpret_cast<const uint4*>(Wt2sw + c * 16384);
    for (int i = tid; i < 2048; i += 256) reinterpret_cast<uint4*>(WB)[i] = src[i];
    __syncthreads();
#pragma unroll
    for (int kcl = 0; kcl < 2; ++kcl) {
      int kc = c * 2 + kcl;
      s16x8 af = *reinterpret_cast<const s16x8*>(&P1[rowA * 264 + kc * 32 + kgrp]);
#pragma unroll
      for (int nt = 0; nt < 16; ++nt) {
        int n = lm + 16 * nt;
        s16x8 bf = *reinterpret_cast<const s16x8*>(&WB[n * 64 + ((kcl * 32 + kgrp) ^ xo)]);
        acc2[nt] = __builtin_amdgcn_mfma_f32_16x16x32_bf16(af, bf, acc2[nt], 0, 0, 0);
      }
    }
    __syncthreads();
  }
#pragma unroll
  for (int nt = 0; nt < 16; ++nt) {
    int n = lm + 16 * nt;
    float bias = bo2[n];
#pragma unroll
    for (int rr = 0; rr < 4; ++rr) {
      float v = acc2[nt][rr] + bias; v = v > 0.f ? v : 0.f;
      out[PRED_OFF + (gr0 + rbase + rr) * 256 + n] = v;
      P1[(rbase + rr) * 264 + n] = f2bf(v);
    }
  }

  {
    const uint4* src = reinterpret_cast<const uint4*>(Wtmusw);
    for (int i = tid; i < 512; i += 256) reinterpret_cast<uint4*>(WB)[i] = src[i];
  }
  __syncthreads();
  f32x4 accm = {0.f, 0.f, 0.f, 0.f};
#pragma unroll
  for (int kc = 0; kc < 8; ++kc) {
    s16x8 af = *reinterpret_cast<const s16x8*>(&P1[rowA * 264 + kc * 32 + kgrp]);
    s16x8 bf = *reinterpret_cast<const s16x8*>(&WB[lm * 256 + ((kc * 32 + kgrp) ^ xo)]);
    accm = __builtin_amdgcn_mfma_f32_16x16x32_bf16(af, bf, accm, 0, 0, 0);
  }
  {
    float bias = bmu[lm];
#pragma unroll
    for (int rr = 0; rr < 4; ++rr) {
      out[(gr0 + rbase + rr) * 16 + lm] = accm[rr] + bias;
    }
  }
}

extern "C" void kernel_launch(void* const* d_in, const int* in_sizes, int n_in,
                              void* d_out, int out_size, void* d_ws, size_t ws_size,
                              hipStream_t stream) {
  const float* inputs = (const float*)d_in[0];
  const float* edges  = (const float*)d_in[1];
  const float* w1     = (const float*)d_in[2];
  const float* b1     = (const float*)d_in[3];
  const float* w2     = (const float*)d_in[4];
  const float* b2     = (const float*)d_in[5];
  const float* wo1    = (const float*)d_in[6];
  const float* bo1    = (const float*)d_in[7];
  const float* wo2    = (const float*)d_in[8];
  const float* bo2    = (const float*)d_in[9];
  const float* wmu    = (const float*)d_in[10];
  const float* bmu    = (const float*)d_in[11];
  float* out = (float*)d_out;

  char* ws = (char*)d_ws;
  float*          agg    = (float*)(ws + 0);
  unsigned short* W2t    = (unsigned short*)(ws + 3276800);
  unsigned short* W1t    = (unsigned short*)(ws + 3282944);
  unsigned short* Wt1sw  = (unsigned short*)(ws + 3295232);
  unsigned short* Wt2sw  = (unsigned short*)(ws + 3328000);
  unsigned short* Wtmusw = (unsigned short*)(ws + 3459072);

  k_tr<<<372, 256, 0, stream>>>(w1, w2, wo1, wo2, wmu, W2t, W1t, Wt1sw, Wt2sw, Wtmusw);
  k_msg<<<512, 512, 0, stream>>>(inputs, edges, b1, b2, W1t, W2t, agg);
  k_out<<<400, 256, 0, stream>>>(inputs, agg, Wt1sw, bo1, Wt2sw, bo2, Wtmusw, bmu, out);
}

// Round 12
// 55.112 us; speedup vs baseline: 3.6730x; 1.0813x over previous
//
#include <hip/hip_runtime.h>
#include <hip/hip_bf16.h>

#define BATCHN 512
#define NV 50
#define NE 2450
#define INSZ 16
#define MH 32
#define NH 256

typedef short s16x8 __attribute__((ext_vector_type(8)));
typedef float f32x4 __attribute__((ext_vector_type(4)));
typedef float f32x2 __attribute__((ext_vector_type(2)));

#define PRED_OFF (BATCHN * NV * INSZ)   // 409600

// ---- ws layout (bytes) ----
// (agg slot unused now)           : 0        .. 3276800
// W2t    bf16 [3][32][32]         : 3276800  .. 3282944
// W1t    bf16 [2][3][32][32]      : 3282944  .. 3295232
// Wt1sw  bf16 16384               : 3295232  .. 3328000
// Wt2sw  bf16 65536               : 3328000  .. 3459072
// Wtmusw bf16 4096                : 3459072  .. 3467264

__device__ __forceinline__ unsigned short f2bf(float x) {
  unsigned int u = __float_as_uint(x);
  unsigned int r = (u + 0x7fffu + ((u >> 16) & 1u)) >> 16;  // RTNE
  return (unsigned short)r;
}
__device__ __forceinline__ unsigned int pk2(float a, float b) {
  return (unsigned int)f2bf(a) | ((unsigned int)f2bf(b) << 16);
}
__device__ __forceinline__ unsigned int cvtpk(float lo, float hi) {
  unsigned int r;
  asm("v_cvt_pk_bf16_f32 %0, %1, %2" : "=v"(r) : "v"(lo), "v"(hi));
  return r;
}
__device__ __forceinline__ unsigned int pkmax0(unsigned int x, unsigned int z) {
  unsigned int r;
  asm("v_pk_max_i16 %0, %1, %2" : "=v"(r) : "v"(x), "v"(z));
  return r;
}
__device__ __forceinline__ f32x2 pkadd(f32x2 a, f32x2 b) {
  f32x2 r;
  asm("v_pk_add_f32 %0, %1, %2" : "=v"(r) : "v"(a), "v"(b));
  return r;
}
__device__ __forceinline__ void pkfma(f32x2& acc, f32x2 a, f32x2 b) {
  asm("v_pk_fma_f32 %0, %1, %2, %0" : "+v"(acc) : "v"(a), "v"(b));
}

// ---------------- Kernel 1: weight transforms -------------------
__global__ void k_tr(const float* __restrict__ w1, const float* __restrict__ w2,
                     const float* __restrict__ wo1, const float* __restrict__ wo2,
                     const float* __restrict__ wmu,
                     unsigned short* __restrict__ W2t, unsigned short* __restrict__ W1t,
                     unsigned short* __restrict__ Wt1sw, unsigned short* __restrict__ Wt2sw,
                     unsigned short* __restrict__ Wtmusw) {
  int idx = blockIdx.x * 256 + threadIdx.x;
  if (idx < 3072) {                      // W2t[kk][h][c] = w2[(kk+1)*32 + c][h]
    int c = idx & 31, h = (idx >> 5) & 31, kk = idx >> 10;
    W2t[idx] = f2bf(w2[((kk + 1) * 32 + c) * 32 + h]);
  } else if (idx < 9216) {               // W1t[half][kk][n][k]
    int j = idx - 3072;
    int k = j & 31, n = (j >> 5) & 31, kk = (j >> 10) % 3, half = j / 3072;
    W1t[j] = f2bf(k < 16 ? w1[((kk + 1) * 32 + half * 16 + k) * 32 + n] : 0.f);
  } else if (idx < 9216 + 16384) {       // Wt1sw
    int j = idx - 9216; int n = j & 255, kl = j >> 8;
    float v = kl < 48 ? wo1[kl * 256 + n] : 0.f;
    Wt1sw[n * 64 + (kl ^ ((n & 7) << 3))] = f2bf(v);
  } else if (idx < 9216 + 16384 + 65536) { // Wt2sw
    int j = idx - (9216 + 16384);
    int c = j >> 14, r = j & 16383;
    int n = r & 255, kl = r >> 8;
    float v = wo2[(c * 64 + kl) * 256 + n];
    Wt2sw[(c * 256 + n) * 64 + (kl ^ ((n & 7) << 3))] = f2bf(v);
  } else if (idx < 9216 + 16384 + 65536 + 4096) { // Wtmusw
    int j = idx - (9216 + 16384 + 65536);
    int n = j & 15, kl = j >> 4;
    Wtmusw[n * 256 + (kl ^ ((n & 7) << 3))] = f2bf(wmu[kl * 16 + n]);
  }
}

// ---------------- Kernel 2: FUSED msg + out-MLP (one block per batch) --------
// 512 blocks x 512 thr (8 waves). Phase 1 = scheme-F messages -> agg in LDS.
// Phase 2 = out-MLP (fc1/fc2/mu) with N-dim split across the 2 wave-halves.
// LDS overlays (phase liveness): S[0,20000) R[20000,40000) E[40000,71200);
// comb overlays R; agg_l[9216,15616) overlays dead S; phase2 aug[0,9216)
// P1[9216,43008) WB[43008,75776) overlay dead phase-1 regions.
__global__ void __launch_bounds__(512, 4)
k_all(const float* __restrict__ inputs, const float* __restrict__ edges,
      const float* __restrict__ b1, const float* __restrict__ b2,
      const unsigned short* __restrict__ W1t, const unsigned short* __restrict__ W2t,
      const unsigned short* __restrict__ Wt1sw, const float* __restrict__ bo1,
      const unsigned short* __restrict__ Wt2sw, const float* __restrict__ bo2,
      const unsigned short* __restrict__ Wtmusw, const float* __restrict__ bmu,
      float* __restrict__ out) {
  __shared__ __align__(16) char smem[75776];
  float* S_lds = (float*)(smem);
  float* R_lds = (float*)(smem + 20000);
  float* E_lds = (float*)(smem + 40000);
  float* comb  = (float*)(smem + 20000);          // overlays dead R
  float* agg_l = (float*)(smem + 9216);           // overlays dead S tail
  unsigned short* aug = (unsigned short*)(smem);  // phase 2
  unsigned short* P1  = (unsigned short*)(smem + 9216);
  unsigned short* WB  = (unsigned short*)(smem + 43008);

  const int b   = blockIdx.x;
  const int tid = threadIdx.x;
  const int w   = tid >> 6;       // 0..7
  const int l   = tid & 63;
  const int grp = l >> 4;         // 0..3
  const int lm  = l & 15;
  const int jt  = w & 3;          // receiver tile / row tile
  const int ih  = w >> 2;         // sender parity / N-half

  // ======================= PHASE 1: messages =======================
  // stage E: E_lds[i][kk][j]; diag/pad = 0
  for (int x = tid; x < NV * 52; x += 512) {
    int i  = x / 52;
    int js = x - i * 52;
    float4 ev = make_float4(0.f, 0.f, 0.f, 0.f);
    if (js < NV && js != i) {
      int e = i * 49 + js - (js > i ? 1 : 0);
      ev = reinterpret_cast<const float4*>(edges)[b * NE + e];
    }
    int base = i * 156 + js;
    E_lds[base]       = ev.y;
    E_lds[base + 52]  = ev.z;
    E_lds[base + 104] = ev.w;
  }

  // in-block fc1 GEMM: R/S = inputs @ W1 halves (K=16 zero-padded)
  {
    const int half = w >> 2;
    const int mt4  = w & 3;
    int node  = mt4 * 16 + lm;
    int nodec = node < NV ? node : NV - 1;
    s16x8 af = {0, 0, 0, 0, 0, 0, 0, 0};
    if (grp < 2) {
      const float4* ip = reinterpret_cast<const float4*>(inputs) + (b * NV + nodec) * 4 + grp * 2;
      float4 x0 = ip[0], x1 = ip[1];
      union { unsigned int u[4]; s16x8 v; } U;
      U.u[0] = cvtpk(x0.x, x0.y); U.u[1] = cvtpk(x0.z, x0.w);
      U.u[2] = cvtpk(x1.x, x1.y); U.u[3] = cvtpk(x1.z, x1.w);
      af = U.v;
    }
    float* dst = half ? S_lds : R_lds;
#pragma unroll
    for (int kk = 0; kk < 3; ++kk) {
#pragma unroll
      for (int nt = 0; nt < 2; ++nt) {
        int h = lm + 16 * nt;
        s16x8 bf = *reinterpret_cast<const s16x8*>(W1t + ((half * 3 + kk) * 32 + h) * 32 + grp * 8);
        f32x4 C;
        if (half == 0) { float bv = b1[(kk + 1) * 32 + h]; C = f32x4{bv, bv, bv, bv}; }
        else C = f32x4{0.f, 0.f, 0.f, 0.f};
        f32x4 o = __builtin_amdgcn_mfma_f32_16x16x32_bf16(af, bf, C, 0, 0, 0);
#pragma unroll
        for (int rr = 0; rr < 4; ++rr) {
          int n2 = mt4 * 16 + grp * 4 + rr;
          if (n2 < NV) dst[n2 * 100 + kk * 32 + h] = o[rr];
        }
      }
    }
  }

  // per-wave persistent fragments
  s16x8 Bf[3][2];
  f32x4 Cb[3][2];
#pragma unroll
  for (int kk = 0; kk < 3; ++kk)
#pragma unroll
    for (int nt = 0; nt < 2; ++nt) {
      int h = lm + 16 * nt;
      Bf[kk][nt] = *reinterpret_cast<const s16x8*>(W2t + (kk * 32 + h) * 32 + grp * 8);
      float bv = b2[(kk + 1) * 32 + h];
      Cb[kk][nt] = f32x4{bv, bv, bv, bv};
    }
  const unsigned int zero = 0;
  __syncthreads();

  // Rreg (as f32x2 pairs) for this wave's 16 receiver rows
  f32x2 Rp2[3][4];
  {
    int jrow = jt * 16 + lm;
    int jr   = jrow < NV ? jrow : NV - 1;
#pragma unroll
    for (int kk = 0; kk < 3; ++kk) {
      const float* Rp = &R_lds[jr * 100 + kk * 32 + grp * 8];
      f32x4 rA = *reinterpret_cast<const f32x4*>(Rp);
      f32x4 rB = *reinterpret_cast<const f32x4*>(Rp + 4);
      Rp2[kk][0] = f32x2{rA[0], rA[1]}; Rp2[kk][1] = f32x2{rA[2], rA[3]};
      Rp2[kk][2] = f32x2{rB[0], rB[1]}; Rp2[kk][3] = f32x2{rB[2], rB[3]};
    }
  }
  __syncthreads();   // R_lds dead (comb overlays it)

  const int slot0 = jt * 16 + grp * 4;
  const bool dead = slot0 > 48;
  const int slot  = dead ? 48 : slot0;

  f32x2 acc0a = {0.f, 0.f}, acc0b = {0.f, 0.f};
  f32x2 acc1a = {0.f, 0.f}, acc1b = {0.f, 0.f};

#pragma unroll 2
  for (int i = ih; i < NV; i += 2) {
    const float* Eb = &E_lds[i * 156 + slot];
#pragma unroll
    for (int kk = 0; kk < 3; ++kk) {
      const float* Sp = &S_lds[i * 100 + kk * 32 + grp * 8];
      f32x4 sA = *reinterpret_cast<const f32x4*>(Sp);
      f32x4 sB = *reinterpret_cast<const f32x4*>(Sp + 4);
      f32x2 t0 = pkadd(Rp2[kk][0], f32x2{sA[0], sA[1]});
      f32x2 t1 = pkadd(Rp2[kk][1], f32x2{sA[2], sA[3]});
      f32x2 t2 = pkadd(Rp2[kk][2], f32x2{sB[0], sB[1]});
      f32x2 t3 = pkadd(Rp2[kk][3], f32x2{sB[2], sB[3]});
      union { unsigned int u[4]; s16x8 v; } U;
      U.u[0] = pkmax0(cvtpk(t0[0], t0[1]), zero);
      U.u[1] = pkmax0(cvtpk(t1[0], t1[1]), zero);
      U.u[2] = pkmax0(cvtpk(t2[0], t2[1]), zero);
      U.u[3] = pkmax0(cvtpk(t3[0], t3[1]), zero);
      f32x4 d0 = __builtin_amdgcn_mfma_f32_16x16x32_bf16(U.v, Bf[kk][0], Cb[kk][0], 0, 0, 0);
      f32x4 d1 = __builtin_amdgcn_mfma_f32_16x16x32_bf16(U.v, Bf[kk][1], Cb[kk][1], 0, 0, 0);
      f32x4 ev = *reinterpret_cast<const f32x4*>(Eb + kk * 52);
      if (dead) ev = f32x4{0.f, 0.f, 0.f, 0.f};
      f32x2 ea = {ev[0], ev[1]}, eb = {ev[2], ev[3]};
      f32x2 r0a = {fmaxf(d0[0], 0.f), fmaxf(d0[1], 0.f)};
      f32x2 r0b = {fmaxf(d0[2], 0.f), fmaxf(d0[3], 0.f)};
      f32x2 r1a = {fmaxf(d1[0], 0.f), fmaxf(d1[1], 0.f)};
      f32x2 r1b = {fmaxf(d1[2], 0.f), fmaxf(d1[3], 0.f)};
      pkfma(acc0a, r0a, ea); pkfma(acc0b, r0b, eb);
      pkfma(acc1a, r1a, ea); pkfma(acc1b, r1b, eb);
    }
  }

  // combine parity waves; write agg into LDS
  if (ih == 1) {
    int cbase = (jt * 64 + l) * 10;
    *reinterpret_cast<f32x2*>(&comb[cbase])     = acc0a;
    *reinterpret_cast<f32x2*>(&comb[cbase + 2]) = acc0b;
    *reinterpret_cast<f32x2*>(&comb[cbase + 4]) = acc1a;
    *reinterpret_cast<f32x2*>(&comb[cbase + 6]) = acc1b;
  }
  __syncthreads();
  if (ih == 0) {
    int cbase = (jt * 64 + l) * 10;
    acc0a += *reinterpret_cast<const f32x2*>(&comb[cbase]);
    acc0b += *reinterpret_cast<const f32x2*>(&comb[cbase + 2]);
    acc1a += *reinterpret_cast<const f32x2*>(&comb[cbase + 4]);
    acc1b += *reinterpret_cast<const f32x2*>(&comb[cbase + 6]);
    float a0v[4] = {acc0a[0], acc0a[1], acc0b[0], acc0b[1]};
    float a1v[4] = {acc1a[0], acc1a[1], acc1b[0], acc1b[1]};
#pragma unroll
    for (int rr = 0; rr < 4; ++rr) {
      int j = jt * 16 + grp * 4 + rr;
      if (j < NV) {
        agg_l[j * 32 + lm]      = a0v[rr];
        agg_l[j * 32 + 16 + lm] = a1v[rr];
      }
    }
  }
  __syncthreads();

  // ======================= PHASE 2: out-MLP =======================
  const int xo = (lm & 7) << 3;

  // aug build (waves 0-3) + stage Wt1sw (all)
  if (tid < 256) {
    int row = tid >> 2, q = tid & 3;
    uint2 u0; uint4 u1;
    if (row < NV) {
      float4 iv = reinterpret_cast<const float4*>(inputs)[(b * NV + row) * 4 + q];
      u0.x = pk2(iv.x, iv.y); u0.y = pk2(iv.z, iv.w);
      f32x4 a0 = *reinterpret_cast<const f32x4*>(&agg_l[row * 32 + q * 8]);
      f32x4 a1 = *reinterpret_cast<const f32x4*>(&agg_l[row * 32 + q * 8 + 4]);
      u1.x = pk2(a0[0], a0[1]); u1.y = pk2(a0[2], a0[3]);
      u1.z = pk2(a1[0], a1[1]); u1.w = pk2(a1[2], a1[3]);
    } else { u0.x = u0.y = 0u; u1.x = u1.y = u1.z = u1.w = 0u; }
    *reinterpret_cast<uint2*>(&aug[row * 72 + q * 4]) = u0;
    *reinterpret_cast<uint4*>(&aug[row * 72 + 16 + q * 8]) = u1;
    uint2 uz; uz.x = 0u; uz.y = 0u;
    *reinterpret_cast<uint2*>(&aug[row * 72 + 48 + q * 4]) = uz;
  }
  {
    const uint4* src = reinterpret_cast<const uint4*>(Wt1sw);
    for (int i2 = tid; i2 < 2048; i2 += 512) reinterpret_cast<uint4*>(WB)[i2] = src[i2];
  }
  __syncthreads();

  const int rowA  = 16 * jt + lm;
  const int kgrp  = grp * 8;
  const int rbase = 16 * jt + grp * 4;
  const int n0    = ih * 8;       // this wave's nt offset

  // fc1: aug[64x64] @ Wt1 -> P1
  f32x4 acc1[8];
#pragma unroll
  for (int nt = 0; nt < 8; ++nt) acc1[nt] = f32x4{0.f, 0.f, 0.f, 0.f};
#pragma unroll
  for (int kc = 0; kc < 2; ++kc) {
    s16x8 af = *reinterpret_cast<const s16x8*>(&aug[rowA * 72 + kc * 32 + kgrp]);
#pragma unroll
    for (int nt = 0; nt < 8; ++nt) {
      int n = lm + 16 * (n0 + nt);
      s16x8 bf = *reinterpret_cast<const s16x8*>(&WB[n * 64 + ((kc * 32 + kgrp) ^ xo)]);
      acc1[nt] = __builtin_amdgcn_mfma_f32_16x16x32_bf16(af, bf, acc1[nt], 0, 0, 0);
    }
  }
#pragma unroll
  for (int nt = 0; nt < 8; ++nt) {
    int n = lm + 16 * (n0 + nt);
    float bias = bo1[n];
#pragma unroll
    for (int rr = 0; rr < 4; ++rr) {
      float v = acc1[nt][rr] + bias; v = v > 0.f ? v : 0.f;
      P1[(rbase + rr) * 264 + n] = f2bf(v);
    }
  }
  __syncthreads();   // WB (Wt1) readers + P1 writers done

  // fc2: P1 @ Wt2 (4 staged chunks)
  f32x4 acc2[8];
#pragma unroll
  for (int nt = 0; nt < 8; ++nt) acc2[nt] = f32x4{0.f, 0.f, 0.f, 0.f};
  for (int c = 0; c < 4; ++c) {
    const uint4* src = reinterpret_cast<const uint4*>(Wt2sw + c * 16384);
    for (int i2 = tid; i2 < 2048; i2 += 512) reinterpret_cast<uint4*>(WB)[i2] = src[i2];
    __syncthreads();
#pragma unroll
    for (int kcl = 0; kcl < 2; ++kcl) {
      int kc = c * 2 + kcl;
      s16x8 af = *reinterpret_cast<const s16x8*>(&P1[rowA * 264 + kc * 32 + kgrp]);
#pragma unroll
      for (int nt = 0; nt < 8; ++nt) {
        int n = lm + 16 * (n0 + nt);
        s16x8 bf = *reinterpret_cast<const s16x8*>(&WB[n * 64 + ((kcl * 32 + kgrp) ^ xo)]);
        acc2[nt] = __builtin_amdgcn_mfma_f32_16x16x32_bf16(af, bf, acc2[nt], 0, 0, 0);
      }
    }
    __syncthreads();
  }
  // epilogue: write pred (f32 out, masked) + P1 bf16 (for mu)
#pragma unroll
  for (int nt = 0; nt < 8; ++nt) {
    int n = lm + 16 * (n0 + nt);
    float bias = bo2[n];
#pragma unroll
    for (int rr = 0; rr < 4; ++rr) {
      int row = rbase + rr;
      float v = acc2[nt][rr] + bias; v = v > 0.f ? v : 0.f;
      if (row < NV) out[PRED_OFF + (b * NV + row) * 256 + n] = v;
      P1[row * 264 + n] = f2bf(v);
    }
  }
  // stage Wtmusw (512 uint4 = one per thread)
  reinterpret_cast<uint4*>(WB)[tid] = reinterpret_cast<const uint4*>(Wtmusw)[tid];
  __syncthreads();

  // mu: pred @ Wtmu (N-half 0 waves only)
  if (ih == 0) {
    f32x4 accm = {0.f, 0.f, 0.f, 0.f};
#pragma unroll
    for (int kc = 0; kc < 8; ++kc) {
      s16x8 af = *reinterpret_cast<const s16x8*>(&P1[rowA * 264 + kc * 32 + kgrp]);
      s16x8 bf = *reinterpret_cast<const s16x8*>(&WB[lm * 256 + ((kc * 32 + kgrp) ^ xo)]);
      accm = __builtin_amdgcn_mfma_f32_16x16x32_bf16(af, bf, accm, 0, 0, 0);
    }
    float bias = bmu[lm];
#pragma unroll
    for (int rr = 0; rr < 4; ++rr) {
      int row = rbase + rr;
      if (row < NV) out[(b * NV + row) * 16 + lm] = accm[rr] + bias;
    }
  }
}

extern "C" void kernel_launch(void* const* d_in, const int* in_sizes, int n_in,
                              void* d_out, int out_size, void* d_ws, size_t ws_size,
                              hipStream_t stream) {
  const float* inputs = (const float*)d_in[0];
  const float* edges  = (const float*)d_in[1];
  const float* w1     = (const float*)d_in[2];
  const float* b1     = (const float*)d_in[3];
  const float* w2     = (const float*)d_in[4];
  const float* b2     = (const float*)d_in[5];
  const float* wo1    = (const float*)d_in[6];
  const float* bo1    = (const float*)d_in[7];
  const float* wo2    = (const float*)d_in[8];
  const float* bo2    = (const float*)d_in[9];
  const float* wmu    = (const float*)d_in[10];
  const float* bmu    = (const float*)d_in[11];
  float* out = (float*)d_out;

  char* ws = (char*)d_ws;
  unsigned short* W2t    = (unsigned short*)(ws + 3276800);
  unsigned short* W1t    = (unsigned short*)(ws + 3282944);
  unsigned short* Wt1sw  = (unsigned short*)(ws + 3295232);
  unsigned short* Wt2sw  = (unsigned short*)(ws + 3328000);
  unsigned short* Wtmusw = (unsigned short*)(ws + 3459072);

  k_tr<<<372, 256, 0, stream>>>(w1, w2, wo1, wo2, wmu, W2t, W1t, Wt1sw, Wt2sw, Wtmusw);
  k_all<<<512, 512, 0, stream>>>(inputs, edges, b1, b2, W1t, W2t,
                                 Wt1sw, bo1, Wt2sw, bo2, Wtmusw, bmu, out);
}